// Round 2
// baseline (780.618 us; speedup 1.0000x reference)
//
#include <hip/hip_runtime.h>

// SoftMoe on MI355X (gfx950).
// Pipeline:
//   conv_x:   x fp32 -> x_hi,x_lo bf16 [b][m][d] + xT bf16 [b][d][m]
//   conv_phi: phi [d][np] fp32 -> phiT_hi/lo bf16 [np][d]
//   conv_w1:  W1 [n][d][h] -> W1T bf16 [n][h][d]
//   gemm<0>:  logits fp32 [b][m][np] = (x_hi+x_lo)*(phi_hi+phi_lo), virtual K=3072
//   rowstats: per (b,m): rowmax, 1/rowsum (softmax over np)  [for Cw/Cm]
//   colpass:  per (b,np): colmax; DwT bf16 [b][np][m] = exp(l - colmax)
//             (unnormalized; 1/colsum folded into gemm<1> epilogue), Cm[b][np]
//   gemm<1>:  Xs bf16 [b][np][d] = DwT * xT, row-scaled by colinv
//   gemm<2>:  per (b,n): relu(Xs*W1T + b1), epilogue contracts with Cm over p
//             -> atomicAdd G[b][n][h]   (Hs never materialized; W2 GEMM deleted)
//   yinit:    Y[b][o] = sum_n (sum_p Cm) * b2[n][o];  gw2: Y += G . W2
//
// Workspace layout (ws_size budget!): peak 224.6 MiB via liveness aliasing:
//   region A (134.2MB): logits, later Xs
//   region B (67.1MB):  xhi|xlo|pTh|pTl during conv+gemm0; DwT from colpass on
//   xT (16.8MB), W1T (16.8MB), stats+G (0.6MB)

#define DI __device__ __forceinline__

typedef __attribute__((ext_vector_type(8))) __bf16 bf16x8;
typedef __attribute__((ext_vector_type(4))) float f32x4;

DI short f2bf(float v) {
  union { float f; unsigned u; } a; a.f = v;
  unsigned u = a.u;
  unsigned r = (u + 0x7FFFu + ((u >> 16) & 1u)) >> 16;  // RNE
  return (short)r;
}
DI float bf2f(short h) {
  union { unsigned u; float f; } a;
  a.u = ((unsigned)(unsigned short)h) << 16;
  return a.f;
}

DI void gload_lds16(const void* g, void* l) {
  __builtin_amdgcn_global_load_lds(
      (__attribute__((address_space(1))) unsigned int*)g,
      (__attribute__((address_space(3))) unsigned int*)l, 16, 0, 0);
}

// ---------------- conversion kernels ----------------

__global__ __launch_bounds__(256) void conv_x(const float* __restrict__ x,
                                              short* __restrict__ xhi,
                                              short* __restrict__ xlo,
                                              short* __restrict__ xT) {
  __shared__ short t0[64][66];
  int b = blockIdx.y;
  int mt = (blockIdx.x >> 4) * 64;
  int dt = (blockIdx.x & 15) * 64;
  int c = threadIdx.x & 63, r0 = threadIdx.x >> 6;
  size_t base = (size_t)b << 20;
#pragma unroll
  for (int i = 0; i < 16; ++i) {
    int r = r0 + i * 4;
    size_t idx = base + (size_t)(mt + r) * 1024 + dt + c;
    float v = x[idx];
    short h = f2bf(v);
    xhi[idx] = h;
    xlo[idx] = f2bf(v - bf2f(h));
    t0[r][c] = h;
  }
  __syncthreads();
#pragma unroll
  for (int i = 0; i < 16; ++i) {
    int u = r0 + i * 4;
    xT[base + (size_t)(dt + u) * 1024 + mt + c] = t0[c][u];
  }
}

__global__ __launch_bounds__(256) void conv_phi(const float* __restrict__ phi,
                                                short* __restrict__ pTh,
                                                short* __restrict__ pTl) {
  __shared__ short th[64][66], tl[64][66];
  int dt = (blockIdx.x >> 6) * 64;
  int pt = (blockIdx.x & 63) * 64;
  int c = threadIdx.x & 63, r0 = threadIdx.x >> 6;
#pragma unroll
  for (int i = 0; i < 16; ++i) {
    int r = r0 + i * 4;
    float v = phi[(size_t)(dt + r) * 4096 + pt + c];
    short h = f2bf(v);
    th[r][c] = h;
    tl[r][c] = f2bf(v - bf2f(h));
  }
  __syncthreads();
#pragma unroll
  for (int i = 0; i < 16; ++i) {
    int u = r0 + i * 4;
    size_t o = (size_t)(pt + u) * 1024 + dt + c;
    pTh[o] = th[c][u];
    pTl[o] = tl[c][u];
  }
}

__global__ __launch_bounds__(256) void conv_w1(const float* __restrict__ W1,
                                               short* __restrict__ W1T) {
  __shared__ short t0[64][66];
  int n = blockIdx.y;
  int dt = (blockIdx.x >> 4) * 64;
  int ht = (blockIdx.x & 15) * 64;
  int c = threadIdx.x & 63, r0 = threadIdx.x >> 6;
  size_t base = (size_t)n << 20;
#pragma unroll
  for (int i = 0; i < 16; ++i) {
    int r = r0 + i * 4;
    t0[r][c] = f2bf(W1[base + (size_t)(dt + r) * 1024 + ht + c]);
  }
  __syncthreads();
#pragma unroll
  for (int i = 0; i < 16; ++i) {
    int u = r0 + i * 4;
    W1T[base + (size_t)(ht + u) * 1024 + dt + c] = t0[c][u];
  }
}

__global__ __launch_bounds__(256) void zeroG(float* __restrict__ G) {
  G[blockIdx.x * 256 + threadIdx.x] = 0.f;
}

// ---------------- GEMM (m97-style 128x128, BK=32, 4 waves) ----------------
// EPI 0: logits (KSEG=3 virtual concat, fp32 out, ldc 4096)
// EPI 1: Xs bf16 out, per-row scale colinv
// EPI 2: relu(+b1), Cm-weighted column sums -> atomicAdd G

template <int EPI>
__global__ __launch_bounds__(256) void gemm_k(
    const short* __restrict__ A0, const short* __restrict__ A1,
    const short* __restrict__ B0, const short* __restrict__ B2,
    float* __restrict__ Cf, short* __restrict__ Cbs,
    const float* __restrict__ rowScale, const float* __restrict__ rowW,
    const float* __restrict__ colBias, float* __restrict__ G) {
  constexpr int KSEG = (EPI == 0) ? 3 : 1;
  constexpr int TILESN = (EPI == 0) ? 32 : 8;
  constexpr size_t ASTR = (EPI == 0) ? (1u << 20) : (EPI == 1 ? (1u << 22) : (1u << 19));
  constexpr size_t BSTR = (EPI == 0) ? 0 : (1u << 20);
  constexpr int BMASK = (EPI == 2) ? 7 : 0xFFFF;

  __shared__ short As[128 * 32];
  __shared__ short Bs[128 * 32];

  int y = blockIdx.y;
  int bx = blockIdx.x;
  int brow = (bx / TILESN) * 128;
  int bcol = (bx % TILESN) * 128;
  int t = threadIdx.x, lane = t & 63, wave = t >> 6;
  int wr = (wave >> 1) * 64, wc = (wave & 1) * 64;

  const short* Abase = A0 + (size_t)y * ASTR;
  const short* A1b = (EPI == 0) ? (A1 + (size_t)y * ASTR) : nullptr;
  const short* Bbase = B0 + (size_t)(y & BMASK) * BSTR;

  f32x4 acc[4][4] = {};

  int srow = wave * 16 + (lane >> 2);  // staging row within 64-row chunk
  int skb = (lane & 3) * 8;            // staging k-element offset
  short* lA = As + t * 8;
  short* lB = Bs + t * 8;

  for (int kt = 0; kt < KSEG * 32; ++kt) {
    const short* Ab = Abase;
    const short* Bb = Bbase;
    if (EPI == 0) {
      int seg = kt >> 5;
      if (seg == 1) Ab = A1b;
      if (seg == 2) Bb = B2;
    }
    int k0 = (kt & 31) * 32;
    __syncthreads();
    {
      const short* ga = Ab + (size_t)(brow + srow) * 1024 + k0 + skb;
      gload_lds16(ga, lA);
      gload_lds16(ga + (size_t)64 * 1024, lA + 64 * 32);
      const short* gb = Bb + (size_t)(bcol + srow) * 1024 + k0 + skb;
      gload_lds16(gb, lB);
      gload_lds16(gb + (size_t)64 * 1024, lB + 64 * 32);
    }
    __syncthreads();
    int fr = lane & 15, fk = (lane >> 4) * 8;
    bf16x8 af[4], bfr[4];
#pragma unroll
    for (int i = 0; i < 4; ++i) af[i] = *(const bf16x8*)(As + (wr + i * 16 + fr) * 32 + fk);
#pragma unroll
    for (int j = 0; j < 4; ++j) bfr[j] = *(const bf16x8*)(Bs + (wc + j * 16 + fr) * 32 + fk);
#pragma unroll
    for (int i = 0; i < 4; ++i)
#pragma unroll
      for (int j = 0; j < 4; ++j)
        acc[i][j] = __builtin_amdgcn_mfma_f32_16x16x32_bf16(af[i], bfr[j], acc[i][j], 0, 0, 0);
  }

  int fc = lane & 15, fq = (lane >> 4) * 4;

  if constexpr (EPI == 0) {
    float* C = Cf + ((size_t)y << 22);
#pragma unroll
    for (int i = 0; i < 4; ++i) {
      int r = brow + wr + i * 16 + fq;
#pragma unroll
      for (int j = 0; j < 4; ++j) {
        int c = bcol + wc + j * 16 + fc;
#pragma unroll
        for (int q = 0; q < 4; ++q) C[(size_t)(r + q) * 4096 + c] = acc[i][j][q];
      }
    }
  } else if constexpr (EPI == 1) {
    short* C = Cbs + ((size_t)y << 22);
    const float* rs = rowScale + ((size_t)y << 12);
#pragma unroll
    for (int i = 0; i < 4; ++i) {
      int r = brow + wr + i * 16 + fq;
#pragma unroll
      for (int j = 0; j < 4; ++j) {
        int c = bcol + wc + j * 16 + fc;
#pragma unroll
        for (int q = 0; q < 4; ++q)
          C[(size_t)(r + q) * 1024 + c] = f2bf(acc[i][j][q] * rs[r + q]);
      }
    }
  } else {
    const float* cmv = rowW + ((size_t)y << 9);          // Cm slab (512 rows)
    const float* bb = colBias + ((size_t)(y & 7) << 10); // b1[n]
    float* g = G + ((size_t)y << 10);
#pragma unroll
    for (int j = 0; j < 4; ++j) {
      int c = bcol + wc + j * 16 + fc;  // h
      float bias = bb[c];
      float sum = 0.f;
#pragma unroll
      for (int i = 0; i < 4; ++i) {
        int r = brow + wr + i * 16 + fq;  // p
#pragma unroll
        for (int q = 0; q < 4; ++q) {
          float h = acc[i][j][q] + bias;
          h = fmaxf(h, 0.f);
          sum += cmv[r + q] * h;
        }
      }
      sum += __shfl_xor(sum, 16);
      sum += __shfl_xor(sum, 32);
      if (fq == 0) atomicAdd(&g[c], sum);
    }
  }
}

// ---------------- softmax stats ----------------

__global__ __launch_bounds__(256) void rowstats(const float* __restrict__ logits,
                                                float* __restrict__ rowmax,
                                                float* __restrict__ rowinv) {
  int bm = blockIdx.x;
  const float* row = logits + (size_t)bm * 4096;
  int tid = threadIdx.x;
  float m = -1e30f;
  for (int i = tid; i < 4096; i += 256) m = fmaxf(m, row[i]);
  for (int d = 32; d; d >>= 1) m = fmaxf(m, __shfl_xor(m, d));
  __shared__ float sm[4];
  if ((tid & 63) == 0) sm[tid >> 6] = m;
  __syncthreads();
  m = fmaxf(fmaxf(sm[0], sm[1]), fmaxf(sm[2], sm[3]));
  float s = 0.f;
  for (int i = tid; i < 4096; i += 256) s += __expf(row[i] - m);
  for (int d = 32; d; d >>= 1) s += __shfl_xor(s, d);
  __shared__ float ss[4];
  if ((tid & 63) == 0) ss[tid >> 6] = s;
  __syncthreads();
  if (tid == 0) {
    rowmax[bm] = m;
    rowinv[bm] = 1.f / (ss[0] + ss[1] + ss[2] + ss[3]);
  }
}

// colmax over m, DwT = exp(l - colmax) (bf16, unnormalized), colinv, Cm.
__global__ __launch_bounds__(256) void colpass(const float* __restrict__ logits,
                                               const float* __restrict__ rowmax,
                                               const float* __restrict__ rowinv,
                                               short* __restrict__ DwT,
                                               float* __restrict__ colinv,
                                               float* __restrict__ Cm) {
  __shared__ float red[4][64];
  __shared__ short tile[64][72];
  int b = blockIdx.y;
  int np0 = blockIdx.x * 64;
  const float* L = logits + ((size_t)b << 22);
  const float* rmax = rowmax + (b << 10);
  const float* rinv = rowinv + (b << 10);
  int tn = threadIdx.x & 63, tm = threadIdx.x >> 6;

  float cmax = -1e30f;
  for (int mi = tm; mi < 1024; mi += 4)
    cmax = fmaxf(cmax, L[(size_t)mi * 4096 + np0 + tn]);
  red[tm][tn] = cmax;
  __syncthreads();
  float CM = fmaxf(fmaxf(red[0][tn], red[1][tn]), fmaxf(red[2][tn], red[3][tn]));

  float csum = 0.f, cms = 0.f;
  for (int mc = 0; mc < 16; ++mc) {
    __syncthreads();
#pragma unroll
    for (int j = 0; j < 16; ++j) {
      int ml = j * 4 + tm;
      int mi = (mc << 6) + ml;
      float v = L[(size_t)mi * 4096 + np0 + tn];
      float e = __expf(v - CM);
      csum += e;
      cms += __expf(v - rmax[mi]) * rinv[mi];
      tile[tn][ml] = f2bf(e);
    }
    __syncthreads();
    int r = threadIdx.x >> 2, q = threadIdx.x & 3;
    short* dst = DwT + (size_t)((b << 12) + np0 + r) * 1024 + (mc << 6) + q * 16;
    const int4* src = (const int4*)&tile[r][q * 16];
    ((int4*)dst)[0] = src[0];
    ((int4*)dst)[1] = src[1];
  }
  __syncthreads();
  red[tm][tn] = csum;
  __syncthreads();
  if (tm == 0) {
    float cs = red[0][tn] + red[1][tn] + red[2][tn] + red[3][tn];
    colinv[(b << 12) + np0 + tn] = 1.f / cs;
  }
  __syncthreads();
  red[tm][tn] = cms;
  __syncthreads();
  if (tm == 0) {
    float c4 = red[0][tn] + red[1][tn] + red[2][tn] + red[3][tn];
    Cm[(b << 12) + np0 + tn] = c4 * (1.f / 1024.f);
  }
}

// ---------------- final combine ----------------

__global__ __launch_bounds__(512) void yinit(const float* __restrict__ Cm,
                                             const float* __restrict__ b2,
                                             float* __restrict__ Y) {
  __shared__ float s[8];
  int b = blockIdx.x;
  int w = threadIdx.x >> 6, l = threadIdx.x & 63;
  float acc = 0.f;
  for (int p = l; p < 512; p += 64) acc += Cm[(b * 8 + w) * 512 + p];
  for (int d = 32; d; d >>= 1) acc += __shfl_xor(acc, d);
  if (l == 0) s[w] = acc;
  __syncthreads();
  int o = threadIdx.x;
  float yv = 0.f;
#pragma unroll
  for (int n = 0; n < 8; ++n) yv += s[n] * b2[n * 512 + o];
  Y[b * 512 + o] = yv;
}

__global__ __launch_bounds__(256) void gw2(const float* __restrict__ G,
                                           const float* __restrict__ W2,
                                           float* __restrict__ Y) {
  int o = blockIdx.x * 256 + threadIdx.x;  // 0..511
  int k0 = blockIdx.y * 256;               // k = n*1024+h, 8192 total
  float acc[8] = {};
  for (int kk = 0; kk < 256; ++kk) {
    int k = k0 + kk;
    float w = W2[(size_t)k * 512 + o];
#pragma unroll
    for (int b = 0; b < 8; ++b) acc[b] += G[b * 8192 + k] * w;
  }
#pragma unroll
  for (int b = 0; b < 8; ++b) atomicAdd(&Y[b * 512 + o], acc[b]);
}

// ---------------- launch ----------------

extern "C" void kernel_launch(void* const* d_in, const int* in_sizes, int n_in,
                              void* d_out, int out_size, void* d_ws, size_t ws_size,
                              hipStream_t stream) {
  const float* x = (const float*)d_in[0];
  const float* phi = (const float*)d_in[1];
  const float* W1 = (const float*)d_in[2];
  const float* b1 = (const float*)d_in[3];
  const float* W2 = (const float*)d_in[4];
  const float* b2 = (const float*)d_in[5];
  float* Y = (float*)d_out;

  size_t off = 0;
  auto alloc = [&](size_t n) {
    void* p = (char*)d_ws + off;
    off += (n + 255) & ~(size_t)255;
    return p;
  };
  // Region A: logits fp32 [8][1024][4096]; Xs bf16 aliases it after colpass.
  float* logits = (float*)alloc(8ull * 1024 * 4096 * 4);  // 134.2 MB
  short* Xs = (short*)logits;
  // Region B: DwT bf16 [8][4096][1024]; conv outputs live here before colpass.
  short* DwT = (short*)alloc(8ull * 4096 * 1024 * 2);  // 67.1 MB
  short* xhi = DwT;                                    // 16.78 MB (dead after gemm0)
  short* xlo = DwT + 8ull * 1024 * 1024;               // 16.78 MB (dead after gemm0)
  short* pTh = DwT + 16ull * 1024 * 1024;              // 8.39 MB (dead after gemm0)
  short* pTl = DwT + 20ull * 1024 * 1024;              // 8.39 MB (dead after gemm0)
  short* xT = (short*)alloc(8ull * 1024 * 1024 * 2);   // 16.78 MB (live thru gemm1)
  short* W1T = (short*)alloc(8ull * 1024 * 1024 * 2);  // 16.78 MB (live thru gemm2)
  float* rowmaxv = (float*)alloc(8192 * 4);
  float* rowinvv = (float*)alloc(8192 * 4);
  float* colinvv = (float*)alloc(32768 * 4);
  float* CmB = (float*)alloc(32768 * 4);
  float* G = (float*)alloc(8ull * 8192 * 4);
  // peak off ~= 224.6 MiB

  conv_x<<<dim3(256, 8), 256, 0, stream>>>(x, xhi, xlo, xT);
  conv_phi<<<dim3(1024), 256, 0, stream>>>(phi, pTh, pTl);
  conv_w1<<<dim3(256, 8), 256, 0, stream>>>(W1, W1T);

  // logits = x_hi*phi_hi + x_lo*phi_hi + x_hi*phi_lo  (virtual K=3072)
  gemm_k<0><<<dim3(256, 8), 256, 0, stream>>>(xhi, xlo, pTh, pTl, logits, nullptr,
                                              nullptr, nullptr, nullptr, nullptr);
  rowstats<<<dim3(8192), 256, 0, stream>>>(logits, rowmaxv, rowinvv);
  colpass<<<dim3(64, 8), 256, 0, stream>>>(logits, rowmaxv, rowinvv, DwT, colinvv, CmB);

  // Xs = (DwT * xT) * colinv   (bf16 out; overwrites logits region)
  gemm_k<1><<<dim3(256, 8), 256, 0, stream>>>(DwT, nullptr, xT, nullptr, nullptr, Xs,
                                              colinvv, nullptr, nullptr, nullptr);

  zeroG<<<dim3(256), 256, 0, stream>>>(G);
  // G[b,n,h] = sum_p Cm * relu(Xs*W1T + b1)
  gemm_k<2><<<dim3(32, 64), 256, 0, stream>>>(Xs, nullptr, W1T, nullptr, nullptr, nullptr,
                                              nullptr, CmB, b1, G);

  yinit<<<dim3(8), 512, 0, stream>>>(CmB, b2, Y);
  gw2<<<dim3(2, 32), 256, 0, stream>>>(G, W2, Y);
}

// Round 3
// 590.127 us; speedup vs baseline: 1.3228x; 1.3228x over previous
//
#include <hip/hip_runtime.h>

// SoftMoe on MI355X (gfx950).
// Pipeline (R2: logits GEMM switched from 3-seg split-bf16 K=3072 to fp16 K=1024;
// error analysis: logit noise sigma~0.013 -> dY ~ 1-3e-3 via Cm path, Dw path ~0
// because softmaxes over std-32 logits are near-one-hot):
//   conv_x:   x fp32 -> xh fp16 [b][m][d] + xT bf16 [b][d][m]
//   conv_phi: phi [d][np] fp32 -> pT fp16 [np][d]
//   conv_w1:  W1 [n][d][h] -> W1T bf16 [n][h][d]
//   gemm<0>:  logits fp32 [b][m][np] = xh * pT  (fp16 MFMA, K=1024)
//   rowstats: per (b,m): rowmax, 1/rowsum (softmax over np)  [for Cw/Cm]
//   colpass:  per (b,np): colmax; DwT bf16 [b][np][m] = exp(l - colmax)
//             (unnormalized; 1/colsum folded into gemm<1> epilogue), Cm[b][np]
//   gemm<1>:  Xs bf16 [b][np][d] = DwT * xT, row-scaled by colinv (bf16 MFMA)
//   gemm<2>:  per (b,n): relu(Xs*W1T + b1), epilogue contracts with Cm over p
//             -> atomicAdd G[b][n][h]   (Hs never materialized; W2 GEMM deleted)
//   yinit:    Y[b][o] = sum_n (sum_p Cm) * b2[n][o];  gw2: Y += G . W2
//
// Workspace (liveness-aliased, peak ~224.6 MiB):
//   region A (134.2MB): logits, later Xs
//   region B (67.1MB):  xh|pT during conv+gemm0; DwT from colpass on
//   xT (16.8MB), W1T (16.8MB), stats+G (0.6MB)

#define DI __device__ __forceinline__

typedef __attribute__((ext_vector_type(8))) __bf16 bf16x8;
typedef __attribute__((ext_vector_type(8))) _Float16 f16x8;
typedef __attribute__((ext_vector_type(4))) float f32x4;

DI short f2bf(float v) {
  union { float f; unsigned u; } a; a.f = v;
  unsigned u = a.u;
  unsigned r = (u + 0x7FFFu + ((u >> 16) & 1u)) >> 16;  // RNE
  return (short)r;
}
DI short f2h(float v) {
  union { _Float16 h[2]; short s[2]; } a;
  a.h[0] = (_Float16)v;  // RNE
  return a.s[0];
}

DI void gload_lds16(const void* g, void* l) {
  __builtin_amdgcn_global_load_lds(
      (__attribute__((address_space(1))) unsigned int*)g,
      (__attribute__((address_space(3))) unsigned int*)l, 16, 0, 0);
}

// ---------------- conversion kernels ----------------

__global__ __launch_bounds__(256) void conv_x(const float* __restrict__ x,
                                              short* __restrict__ xh,
                                              short* __restrict__ xT) {
  __shared__ short t0[64][66];
  int b = blockIdx.y;
  int mt = (blockIdx.x >> 4) * 64;
  int dt = (blockIdx.x & 15) * 64;
  int c = threadIdx.x & 63, r0 = threadIdx.x >> 6;
  size_t base = (size_t)b << 20;
#pragma unroll
  for (int i = 0; i < 16; ++i) {
    int r = r0 + i * 4;
    size_t idx = base + (size_t)(mt + r) * 1024 + dt + c;
    float v = x[idx];
    xh[idx] = f2h(v);
    t0[r][c] = f2bf(v);
  }
  __syncthreads();
#pragma unroll
  for (int i = 0; i < 16; ++i) {
    int u = r0 + i * 4;
    xT[base + (size_t)(dt + u) * 1024 + mt + c] = t0[c][u];
  }
}

__global__ __launch_bounds__(256) void conv_phi(const float* __restrict__ phi,
                                                short* __restrict__ pT) {
  __shared__ short th[64][66];
  int dt = (blockIdx.x >> 6) * 64;
  int pt = (blockIdx.x & 63) * 64;
  int c = threadIdx.x & 63, r0 = threadIdx.x >> 6;
#pragma unroll
  for (int i = 0; i < 16; ++i) {
    int r = r0 + i * 4;
    th[r][c] = f2h(phi[(size_t)(dt + r) * 4096 + pt + c]);
  }
  __syncthreads();
#pragma unroll
  for (int i = 0; i < 16; ++i) {
    int u = r0 + i * 4;
    pT[(size_t)(pt + u) * 1024 + dt + c] = th[c][u];
  }
}

__global__ __launch_bounds__(256) void conv_w1(const float* __restrict__ W1,
                                               short* __restrict__ W1T) {
  __shared__ short t0[64][66];
  int n = blockIdx.y;
  int dt = (blockIdx.x >> 4) * 64;
  int ht = (blockIdx.x & 15) * 64;
  int c = threadIdx.x & 63, r0 = threadIdx.x >> 6;
  size_t base = (size_t)n << 20;
#pragma unroll
  for (int i = 0; i < 16; ++i) {
    int r = r0 + i * 4;
    t0[r][c] = f2bf(W1[base + (size_t)(dt + r) * 1024 + ht + c]);
  }
  __syncthreads();
#pragma unroll
  for (int i = 0; i < 16; ++i) {
    int u = r0 + i * 4;
    W1T[base + (size_t)(ht + u) * 1024 + dt + c] = t0[c][u];
  }
}

__global__ __launch_bounds__(256) void zeroG(float* __restrict__ G) {
  G[blockIdx.x * 256 + threadIdx.x] = 0.f;
}

// ---------------- GEMM (m97-style 128x128, BK=32, 4 waves) ----------------
// EPI 0: logits fp32 out (fp16 MFMA, ldc 4096)
// EPI 1: Xs bf16 out, per-row scale colinv (bf16 MFMA)
// EPI 2: relu(+b1), Cm-weighted column sums -> atomicAdd G (bf16 MFMA)

template <int EPI>
__global__ __launch_bounds__(256) void gemm_k(
    const short* __restrict__ A0, const short* __restrict__ B0,
    float* __restrict__ Cf, short* __restrict__ Cbs,
    const float* __restrict__ rowScale, const float* __restrict__ rowW,
    const float* __restrict__ colBias, float* __restrict__ G) {
  constexpr int TILESN = (EPI == 0) ? 32 : 8;
  constexpr size_t ASTR = (EPI == 0) ? (1u << 20) : (EPI == 1 ? (1u << 22) : (1u << 19));
  constexpr size_t BSTR = (EPI == 0) ? 0 : (1u << 20);
  constexpr int BMASK = (EPI == 2) ? 7 : 0xFFFF;

  __shared__ short As[128 * 32];
  __shared__ short Bs[128 * 32];

  int y = blockIdx.y;
  int bx = blockIdx.x;
  int brow = (bx / TILESN) * 128;
  int bcol = (bx % TILESN) * 128;
  int t = threadIdx.x, lane = t & 63, wave = t >> 6;
  int wr = (wave >> 1) * 64, wc = (wave & 1) * 64;

  const short* Abase = A0 + (size_t)y * ASTR;
  const short* Bbase = B0 + (size_t)(y & BMASK) * BSTR;

  f32x4 acc[4][4] = {};

  int srow = wave * 16 + (lane >> 2);  // staging row within 64-row chunk
  int skb = (lane & 3) * 8;            // staging k-element offset
  short* lA = As + t * 8;
  short* lB = Bs + t * 8;

  for (int kt = 0; kt < 32; ++kt) {
    int k0 = kt * 32;
    __syncthreads();
    {
      const short* ga = Abase + (size_t)(brow + srow) * 1024 + k0 + skb;
      gload_lds16(ga, lA);
      gload_lds16(ga + (size_t)64 * 1024, lA + 64 * 32);
      const short* gb = Bbase + (size_t)(bcol + srow) * 1024 + k0 + skb;
      gload_lds16(gb, lB);
      gload_lds16(gb + (size_t)64 * 1024, lB + 64 * 32);
    }
    __syncthreads();
    int fr = lane & 15, fk = (lane >> 4) * 8;
    if constexpr (EPI == 0) {
      f16x8 af[4], bfr[4];
#pragma unroll
      for (int i = 0; i < 4; ++i) af[i] = *(const f16x8*)(As + (wr + i * 16 + fr) * 32 + fk);
#pragma unroll
      for (int j = 0; j < 4; ++j) bfr[j] = *(const f16x8*)(Bs + (wc + j * 16 + fr) * 32 + fk);
#pragma unroll
      for (int i = 0; i < 4; ++i)
#pragma unroll
        for (int j = 0; j < 4; ++j)
          acc[i][j] = __builtin_amdgcn_mfma_f32_16x16x32_f16(af[i], bfr[j], acc[i][j], 0, 0, 0);
    } else {
      bf16x8 af[4], bfr[4];
#pragma unroll
      for (int i = 0; i < 4; ++i) af[i] = *(const bf16x8*)(As + (wr + i * 16 + fr) * 32 + fk);
#pragma unroll
      for (int j = 0; j < 4; ++j) bfr[j] = *(const bf16x8*)(Bs + (wc + j * 16 + fr) * 32 + fk);
#pragma unroll
      for (int i = 0; i < 4; ++i)
#pragma unroll
        for (int j = 0; j < 4; ++j)
          acc[i][j] = __builtin_amdgcn_mfma_f32_16x16x32_bf16(af[i], bfr[j], acc[i][j], 0, 0, 0);
    }
  }

  int fc = lane & 15, fq = (lane >> 4) * 4;

  if constexpr (EPI == 0) {
    float* C = Cf + ((size_t)y << 22);
#pragma unroll
    for (int i = 0; i < 4; ++i) {
      int r = brow + wr + i * 16 + fq;
#pragma unroll
      for (int j = 0; j < 4; ++j) {
        int c = bcol + wc + j * 16 + fc;
#pragma unroll
        for (int q = 0; q < 4; ++q) C[(size_t)(r + q) * 4096 + c] = acc[i][j][q];
      }
    }
  } else if constexpr (EPI == 1) {
    short* C = Cbs + ((size_t)y << 22);
    const float* rs = rowScale + ((size_t)y << 12);
#pragma unroll
    for (int i = 0; i < 4; ++i) {
      int r = brow + wr + i * 16 + fq;
#pragma unroll
      for (int j = 0; j < 4; ++j) {
        int c = bcol + wc + j * 16 + fc;
#pragma unroll
        for (int q = 0; q < 4; ++q)
          C[(size_t)(r + q) * 1024 + c] = f2bf(acc[i][j][q] * rs[r + q]);
      }
    }
  } else {
    const float* cmv = rowW + ((size_t)y << 9);          // Cm slab (512 rows)
    const float* bb = colBias + ((size_t)(y & 7) << 10); // b1[n]
    float* g = G + ((size_t)y << 10);
#pragma unroll
    for (int j = 0; j < 4; ++j) {
      int c = bcol + wc + j * 16 + fc;  // h
      float bias = bb[c];
      float sum = 0.f;
#pragma unroll
      for (int i = 0; i < 4; ++i) {
        int r = brow + wr + i * 16 + fq;  // p
#pragma unroll
        for (int q = 0; q < 4; ++q) {
          float h = acc[i][j][q] + bias;
          h = fmaxf(h, 0.f);
          sum += cmv[r + q] * h;
        }
      }
      sum += __shfl_xor(sum, 16);
      sum += __shfl_xor(sum, 32);
      if (fq == 0) atomicAdd(&g[c], sum);
    }
  }
}

// ---------------- softmax stats ----------------

__global__ __launch_bounds__(256) void rowstats(const float* __restrict__ logits,
                                                float* __restrict__ rowmax,
                                                float* __restrict__ rowinv) {
  int bm = blockIdx.x;
  const float* row = logits + (size_t)bm * 4096;
  int tid = threadIdx.x;
  float m = -1e30f;
  for (int i = tid; i < 4096; i += 256) m = fmaxf(m, row[i]);
  for (int d = 32; d; d >>= 1) m = fmaxf(m, __shfl_xor(m, d));
  __shared__ float sm[4];
  if ((tid & 63) == 0) sm[tid >> 6] = m;
  __syncthreads();
  m = fmaxf(fmaxf(sm[0], sm[1]), fmaxf(sm[2], sm[3]));
  float s = 0.f;
  for (int i = tid; i < 4096; i += 256) s += __expf(row[i] - m);
  for (int d = 32; d; d >>= 1) s += __shfl_xor(s, d);
  __shared__ float ss[4];
  if ((tid & 63) == 0) ss[tid >> 6] = s;
  __syncthreads();
  if (tid == 0) {
    rowmax[bm] = m;
    rowinv[bm] = 1.f / (ss[0] + ss[1] + ss[2] + ss[3]);
  }
}

// colmax over m, DwT = exp(l - colmax) (bf16, unnormalized), colinv, Cm.
__global__ __launch_bounds__(256) void colpass(const float* __restrict__ logits,
                                               const float* __restrict__ rowmax,
                                               const float* __restrict__ rowinv,
                                               short* __restrict__ DwT,
                                               float* __restrict__ colinv,
                                               float* __restrict__ Cm) {
  __shared__ float red[4][64];
  __shared__ short tile[64][72];
  int b = blockIdx.y;
  int np0 = blockIdx.x * 64;
  const float* L = logits + ((size_t)b << 22);
  const float* rmax = rowmax + (b << 10);
  const float* rinv = rowinv + (b << 10);
  int tn = threadIdx.x & 63, tm = threadIdx.x >> 6;

  float cmax = -1e30f;
  for (int mi = tm; mi < 1024; mi += 4)
    cmax = fmaxf(cmax, L[(size_t)mi * 4096 + np0 + tn]);
  red[tm][tn] = cmax;
  __syncthreads();
  float CM = fmaxf(fmaxf(red[0][tn], red[1][tn]), fmaxf(red[2][tn], red[3][tn]));

  float csum = 0.f, cms = 0.f;
  for (int mc = 0; mc < 16; ++mc) {
    __syncthreads();
#pragma unroll
    for (int j = 0; j < 16; ++j) {
      int ml = j * 4 + tm;
      int mi = (mc << 6) + ml;
      float v = L[(size_t)mi * 4096 + np0 + tn];
      float e = __expf(v - CM);
      csum += e;
      cms += __expf(v - rmax[mi]) * rinv[mi];
      tile[tn][ml] = f2bf(e);
    }
    __syncthreads();
    int r = threadIdx.x >> 2, q = threadIdx.x & 3;
    short* dst = DwT + (size_t)((b << 12) + np0 + r) * 1024 + (mc << 6) + q * 16;
    const int4* src = (const int4*)&tile[r][q * 16];
    ((int4*)dst)[0] = src[0];
    ((int4*)dst)[1] = src[1];
  }
  __syncthreads();
  red[tm][tn] = csum;
  __syncthreads();
  if (tm == 0) {
    float cs = red[0][tn] + red[1][tn] + red[2][tn] + red[3][tn];
    colinv[(b << 12) + np0 + tn] = 1.f / cs;
  }
  __syncthreads();
  red[tm][tn] = cms;
  __syncthreads();
  if (tm == 0) {
    float c4 = red[0][tn] + red[1][tn] + red[2][tn] + red[3][tn];
    Cm[(b << 12) + np0 + tn] = c4 * (1.f / 1024.f);
  }
}

// ---------------- final combine ----------------

__global__ __launch_bounds__(512) void yinit(const float* __restrict__ Cm,
                                             const float* __restrict__ b2,
                                             float* __restrict__ Y) {
  __shared__ float s[8];
  int b = blockIdx.x;
  int w = threadIdx.x >> 6, l = threadIdx.x & 63;
  float acc = 0.f;
  for (int p = l; p < 512; p += 64) acc += Cm[(b * 8 + w) * 512 + p];
  for (int d = 32; d; d >>= 1) acc += __shfl_xor(acc, d);
  if (l == 0) s[w] = acc;
  __syncthreads();
  int o = threadIdx.x;
  float yv = 0.f;
#pragma unroll
  for (int n = 0; n < 8; ++n) yv += s[n] * b2[n * 512 + o];
  Y[b * 512 + o] = yv;
}

__global__ __launch_bounds__(256) void gw2(const float* __restrict__ G,
                                           const float* __restrict__ W2,
                                           float* __restrict__ Y) {
  int o = blockIdx.x * 256 + threadIdx.x;  // 0..511
  int k0 = blockIdx.y * 256;               // k = n*1024+h, 8192 total
  float acc[8] = {};
  for (int kk = 0; kk < 256; ++kk) {
    int k = k0 + kk;
    float w = W2[(size_t)k * 512 + o];
#pragma unroll
    for (int b = 0; b < 8; ++b) acc[b] += G[b * 8192 + k] * w;
  }
#pragma unroll
  for (int b = 0; b < 8; ++b) atomicAdd(&Y[b * 512 + o], acc[b]);
}

// ---------------- launch ----------------

extern "C" void kernel_launch(void* const* d_in, const int* in_sizes, int n_in,
                              void* d_out, int out_size, void* d_ws, size_t ws_size,
                              hipStream_t stream) {
  const float* x = (const float*)d_in[0];
  const float* phi = (const float*)d_in[1];
  const float* W1 = (const float*)d_in[2];
  const float* b1 = (const float*)d_in[3];
  const float* W2 = (const float*)d_in[4];
  const float* b2 = (const float*)d_in[5];
  float* Y = (float*)d_out;

  size_t off = 0;
  auto alloc = [&](size_t n) {
    void* p = (char*)d_ws + off;
    off += (n + 255) & ~(size_t)255;
    return p;
  };
  // Region A: logits fp32 [8][1024][4096]; Xs bf16 aliases it after colpass.
  float* logits = (float*)alloc(8ull * 1024 * 4096 * 4);  // 134.2 MB
  short* Xs = (short*)logits;
  // Region B: DwT bf16 [8][4096][1024]; conv outputs live here before colpass.
  short* DwT = (short*)alloc(8ull * 4096 * 1024 * 2);  // 67.1 MB
  short* xh = DwT;                                     // fp16, 16.78 MB (dead after gemm0)
  short* pT = DwT + 8ull * 1024 * 1024;                // fp16, 8.39 MB (dead after gemm0)
  short* xT = (short*)alloc(8ull * 1024 * 1024 * 2);   // bf16, live thru gemm1
  short* W1T = (short*)alloc(8ull * 1024 * 1024 * 2);  // bf16, live thru gemm2
  float* rowmaxv = (float*)alloc(8192 * 4);
  float* rowinvv = (float*)alloc(8192 * 4);
  float* colinvv = (float*)alloc(32768 * 4);
  float* CmB = (float*)alloc(32768 * 4);
  float* G = (float*)alloc(8ull * 8192 * 4);
  // peak off ~= 224.6 MiB

  conv_x<<<dim3(256, 8), 256, 0, stream>>>(x, xh, xT);
  conv_phi<<<dim3(1024), 256, 0, stream>>>(phi, pT);
  conv_w1<<<dim3(256, 8), 256, 0, stream>>>(W1, W1T);

  // logits = xh * pT  (fp16 MFMA, K=1024)
  gemm_k<0><<<dim3(256, 8), 256, 0, stream>>>(xh, pT, logits, nullptr,
                                              nullptr, nullptr, nullptr, nullptr);
  rowstats<<<dim3(8192), 256, 0, stream>>>(logits, rowmaxv, rowinvv);
  colpass<<<dim3(64, 8), 256, 0, stream>>>(logits, rowmaxv, rowinvv, DwT, colinvv, CmB);

  // Xs = (DwT * xT) * colinv   (bf16 out; overwrites logits region)
  gemm_k<1><<<dim3(256, 8), 256, 0, stream>>>(DwT, xT, nullptr, Xs,
                                              colinvv, nullptr, nullptr, nullptr);

  zeroG<<<dim3(256), 256, 0, stream>>>(G);
  // G[b,n,h] = sum_p Cm * relu(Xs*W1T + b1)
  gemm_k<2><<<dim3(32, 64), 256, 0, stream>>>(Xs, W1T, nullptr, nullptr,
                                              nullptr, CmB, b1, G);

  yinit<<<dim3(8), 512, 0, stream>>>(CmB, b2, Y);
  gw2<<<dim3(2, 32), 256, 0, stream>>>(G, W2, Y);
}

// Round 4
// 414.991 us; speedup vs baseline: 1.8810x; 1.4220x over previous
//
#include <hip/hip_runtime.h>

// SoftMoe on MI355X (gfx950).
// R4 restructure: fp32 logits buffer eliminated.
//   conv_x:   x fp32 -> xh fp16 [b][m][d] + xT bf16 [b][d][m]
//   conv_phi: phi [d][np] fp32 -> pT fp16 [np][d]
//   conv_w1:  W1 [n][d][h] -> W1T bf16 [n][h][d]
//   gemm<0>:  LT fp16 [b][np][m] = (xh * pT)^T  (fp16 MFMA, K=1024, transposed
//             register->global write) + per-(m, 64np-chunk) softmax partials
//             (max, sumexp) for the Cw row-softmax -> Pr
//   rowfin:   merge Pr chunks -> rowmax/rowinv per (b,m)
//   rowpass:  per (b,np) row of LT (contiguous!): colmax, DwT bf16 = exp(l-colmax)
//             (unnormalized; 1/colsum folded into gemm<1>), colinv, Cm
//   gemm<1>:  Xs bf16 [b][np][d] = DwT * xT, row-scaled by colinv (bf16 MFMA)
//   gemm<2>:  relu(Xs*W1T + b1), epilogue contracts with Cm over p -> atomicAdd G
//   yinit:    Y[b][o] = sum_n (sum_p Cm) * b2[n][o];  gw2: Y += G . W2
//
// Workspace (liveness-aliased, peak ~172 MiB):
//   region A (67.1MB): LT, later Xs       region B (67.1MB): xh|pT, later DwT
//   xT (16.8MB), W1T (16.8MB), Pr (4MB), stats+G (0.6MB)

#define DI __device__ __forceinline__

typedef __attribute__((ext_vector_type(8))) __bf16 bf16x8;
typedef __attribute__((ext_vector_type(8))) _Float16 f16x8;
typedef __attribute__((ext_vector_type(4))) float f32x4;

DI short f2bf(float v) {
  union { float f; unsigned u; } a; a.f = v;
  unsigned u = a.u;
  unsigned r = (u + 0x7FFFu + ((u >> 16) & 1u)) >> 16;  // RNE
  return (short)r;
}
DI short f2h(float v) {
  union { _Float16 h[2]; short s[2]; } a;
  a.h[0] = (_Float16)v;  // RNE
  return a.s[0];
}

DI void gload_lds16(const void* g, void* l) {
  __builtin_amdgcn_global_load_lds(
      (__attribute__((address_space(1))) unsigned int*)g,
      (__attribute__((address_space(3))) unsigned int*)l, 16, 0, 0);
}

// ---------------- conversion kernels ----------------

__global__ __launch_bounds__(256) void conv_x(const float* __restrict__ x,
                                              short* __restrict__ xh,
                                              short* __restrict__ xT) {
  __shared__ short t0[64][66];
  int b = blockIdx.y;
  int mt = (blockIdx.x >> 4) * 64;
  int dt = (blockIdx.x & 15) * 64;
  int c = threadIdx.x & 63, r0 = threadIdx.x >> 6;
  size_t base = (size_t)b << 20;
#pragma unroll
  for (int i = 0; i < 16; ++i) {
    int r = r0 + i * 4;
    size_t idx = base + (size_t)(mt + r) * 1024 + dt + c;
    float v = x[idx];
    xh[idx] = f2h(v);
    t0[r][c] = f2bf(v);
  }
  __syncthreads();
#pragma unroll
  for (int i = 0; i < 16; ++i) {
    int u = r0 + i * 4;
    xT[base + (size_t)(dt + u) * 1024 + mt + c] = t0[c][u];
  }
}

__global__ __launch_bounds__(256) void conv_phi(const float* __restrict__ phi,
                                                short* __restrict__ pT) {
  __shared__ short th[64][66];
  int dt = (blockIdx.x >> 6) * 64;
  int pt = (blockIdx.x & 63) * 64;
  int c = threadIdx.x & 63, r0 = threadIdx.x >> 6;
#pragma unroll
  for (int i = 0; i < 16; ++i) {
    int r = r0 + i * 4;
    th[r][c] = f2h(phi[(size_t)(dt + r) * 4096 + pt + c]);
  }
  __syncthreads();
#pragma unroll
  for (int i = 0; i < 16; ++i) {
    int u = r0 + i * 4;
    pT[(size_t)(pt + u) * 1024 + dt + c] = th[c][u];
  }
}

__global__ __launch_bounds__(256) void conv_w1(const float* __restrict__ W1,
                                               short* __restrict__ W1T) {
  __shared__ short t0[64][66];
  int n = blockIdx.y;
  int dt = (blockIdx.x >> 4) * 64;
  int ht = (blockIdx.x & 15) * 64;
  int c = threadIdx.x & 63, r0 = threadIdx.x >> 6;
  size_t base = (size_t)n << 20;
#pragma unroll
  for (int i = 0; i < 16; ++i) {
    int r = r0 + i * 4;
    t0[r][c] = f2bf(W1[base + (size_t)(dt + r) * 1024 + ht + c]);
  }
  __syncthreads();
#pragma unroll
  for (int i = 0; i < 16; ++i) {
    int u = r0 + i * 4;
    W1T[base + (size_t)(ht + u) * 1024 + dt + c] = t0[c][u];
  }
}

__global__ __launch_bounds__(256) void zeroG(float* __restrict__ G) {
  G[blockIdx.x * 256 + threadIdx.x] = 0.f;
}

// ---------------- GEMM (m97-style 128x128, BK=32, 4 waves) ----------------
// EPI 0: LT fp16 transposed out + Cw row-softmax partials (fp16 MFMA)
// EPI 1: Xs bf16 out, per-row scale colinv (bf16 MFMA)
// EPI 2: relu(+b1), Cm-weighted column sums -> atomicAdd G (bf16 MFMA)

template <int EPI>
__global__ __launch_bounds__(256) void gemm_k(
    const short* __restrict__ A0, const short* __restrict__ B0,
    float* __restrict__ Cf, short* __restrict__ Cbs,
    const float* __restrict__ rowScale, const float* __restrict__ rowW,
    const float* __restrict__ colBias, float* __restrict__ G) {
  constexpr int TILESN = (EPI == 0) ? 32 : 8;
  constexpr size_t ASTR = (EPI == 0) ? (1u << 20) : (EPI == 1 ? (1u << 22) : (1u << 19));
  constexpr size_t BSTR = (EPI == 0) ? 0 : (1u << 20);
  constexpr int BMASK = (EPI == 2) ? 7 : 0xFFFF;

  __shared__ short As[128 * 32];
  __shared__ short Bs[128 * 32];

  int y = blockIdx.y;
  int bx = blockIdx.x;
  int brow = (bx / TILESN) * 128;
  int bcol = (bx % TILESN) * 128;
  int t = threadIdx.x, lane = t & 63, wave = t >> 6;
  int wr = (wave >> 1) * 64, wc = (wave & 1) * 64;

  const short* Abase = A0 + (size_t)y * ASTR;
  const short* Bbase = B0 + (size_t)(y & BMASK) * BSTR;

  f32x4 acc[4][4] = {};

  int srow = wave * 16 + (lane >> 2);  // staging row within 64-row chunk
  int skb = (lane & 3) * 8;            // staging k-element offset
  short* lA = As + t * 8;
  short* lB = Bs + t * 8;

  for (int kt = 0; kt < 32; ++kt) {
    int k0 = kt * 32;
    __syncthreads();
    {
      const short* ga = Abase + (size_t)(brow + srow) * 1024 + k0 + skb;
      gload_lds16(ga, lA);
      gload_lds16(ga + (size_t)64 * 1024, lA + 64 * 32);
      const short* gb = Bbase + (size_t)(bcol + srow) * 1024 + k0 + skb;
      gload_lds16(gb, lB);
      gload_lds16(gb + (size_t)64 * 1024, lB + 64 * 32);
    }
    __syncthreads();
    int fr = lane & 15, fk = (lane >> 4) * 8;
    if constexpr (EPI == 0) {
      f16x8 af[4], bfr[4];
#pragma unroll
      for (int i = 0; i < 4; ++i) af[i] = *(const f16x8*)(As + (wr + i * 16 + fr) * 32 + fk);
#pragma unroll
      for (int j = 0; j < 4; ++j) bfr[j] = *(const f16x8*)(Bs + (wc + j * 16 + fr) * 32 + fk);
#pragma unroll
      for (int i = 0; i < 4; ++i)
#pragma unroll
        for (int j = 0; j < 4; ++j)
          acc[i][j] = __builtin_amdgcn_mfma_f32_16x16x32_f16(af[i], bfr[j], acc[i][j], 0, 0, 0);
    } else {
      bf16x8 af[4], bfr[4];
#pragma unroll
      for (int i = 0; i < 4; ++i) af[i] = *(const bf16x8*)(As + (wr + i * 16 + fr) * 32 + fk);
#pragma unroll
      for (int j = 0; j < 4; ++j) bfr[j] = *(const bf16x8*)(Bs + (wc + j * 16 + fr) * 32 + fk);
#pragma unroll
      for (int i = 0; i < 4; ++i)
#pragma unroll
        for (int j = 0; j < 4; ++j)
          acc[i][j] = __builtin_amdgcn_mfma_f32_16x16x32_bf16(af[i], bfr[j], acc[i][j], 0, 0, 0);
    }
  }

  int fc = lane & 15, fq = (lane >> 4) * 4;

  if constexpr (EPI == 0) {
    // 1) transposed fp16 write: LT[np][m], per (i,j) 4 m-contiguous values
    short* LT = Cbs + ((size_t)y << 22);
#pragma unroll
    for (int i = 0; i < 4; ++i) {
      int r0 = brow + wr + i * 16 + fq;
#pragma unroll
      for (int j = 0; j < 4; ++j) {
        int c = bcol + wc + j * 16 + fc;
        union { short s[4]; int2 v2; } pk;
#pragma unroll
        for (int q = 0; q < 4; ++q) pk.s[q] = f2h(acc[i][j][q]);
        *(int2*)(LT + ((size_t)c << 10) + r0) = pk.v2;
      }
    }
    // 2) Cw row-softmax partials over this wave-column's 64-np span
    float* Pr = Cf + ((size_t)y << 17);  // [1024 m][64 chunks] float2
    int chunk = (bcol >> 6) + (wave & 1);
#pragma unroll
    for (int i = 0; i < 4; ++i) {
#pragma unroll
      for (int q = 0; q < 4; ++q) {
        float vm = fmaxf(fmaxf(acc[i][0][q], acc[i][1][q]),
                         fmaxf(acc[i][2][q], acc[i][3][q]));
#pragma unroll
        for (int d = 1; d < 16; d <<= 1) vm = fmaxf(vm, __shfl_xor(vm, d));
        float s = 0.f;
#pragma unroll
        for (int j = 0; j < 4; ++j) s += __expf(acc[i][j][q] - vm);
#pragma unroll
        for (int d = 1; d < 16; d <<= 1) s += __shfl_xor(s, d);
        if (fc == 0) {
          int m = brow + wr + i * 16 + fq + q;
          *(float2*)(Pr + ((size_t)m * 64 + chunk) * 2) = make_float2(vm, s);
        }
      }
    }
  } else if constexpr (EPI == 1) {
    short* C = Cbs + ((size_t)y << 22);
    const float* rs = rowScale + ((size_t)y << 12);
#pragma unroll
    for (int i = 0; i < 4; ++i) {
      int r = brow + wr + i * 16 + fq;
#pragma unroll
      for (int j = 0; j < 4; ++j) {
        int c = bcol + wc + j * 16 + fc;
#pragma unroll
        for (int q = 0; q < 4; ++q)
          C[(size_t)(r + q) * 1024 + c] = f2bf(acc[i][j][q] * rs[r + q]);
      }
    }
  } else {
    const float* cmv = rowW + ((size_t)y << 9);          // Cm slab (512 rows)
    const float* bb = colBias + ((size_t)(y & 7) << 10); // b1[n]
    float* g = G + ((size_t)y << 10);
#pragma unroll
    for (int j = 0; j < 4; ++j) {
      int c = bcol + wc + j * 16 + fc;  // h
      float bias = bb[c];
      float sum = 0.f;
#pragma unroll
      for (int i = 0; i < 4; ++i) {
        int r = brow + wr + i * 16 + fq;  // p
#pragma unroll
        for (int q = 0; q < 4; ++q) {
          float h = acc[i][j][q] + bias;
          h = fmaxf(h, 0.f);
          sum += cmv[r + q] * h;
        }
      }
      sum += __shfl_xor(sum, 16);
      sum += __shfl_xor(sum, 32);
      if (fq == 0) atomicAdd(&g[c], sum);
    }
  }
}

// ---------------- softmax stage ----------------

// merge per-chunk (max,sumexp) partials -> rowmax, rowinv per (b,m)
__global__ __launch_bounds__(256) void rowfin(const float* __restrict__ Pr,
                                              float* __restrict__ rowmax,
                                              float* __restrict__ rowinv) {
  int row = blockIdx.x * 4 + (threadIdx.x >> 6);  // global b*1024+m
  int lane = threadIdx.x & 63;
  float2 p = ((const float2*)Pr)[(size_t)row * 64 + lane];
  float vm = p.x;
#pragma unroll
  for (int d = 1; d < 64; d <<= 1) vm = fmaxf(vm, __shfl_xor(vm, d));
  float s = p.y * __expf(p.x - vm);
#pragma unroll
  for (int d = 1; d < 64; d <<= 1) s += __shfl_xor(s, d);
  if (lane == 0) {
    rowmax[row] = vm;
    rowinv[row] = 1.f / s;
  }
}

// per (b,np) row of LT: colmax, DwT bf16 = exp(l-colmax), colinv, Cm
__global__ __launch_bounds__(256) void rowpass(const short* __restrict__ LT,
                                               const float* __restrict__ rowmax,
                                               const float* __restrict__ rowinv,
                                               short* __restrict__ DwT,
                                               float* __restrict__ colinv,
                                               float* __restrict__ Cm) {
  int b = blockIdx.y;
  int np0 = blockIdx.x * 64;
  int wave = threadIdx.x >> 6, lane = threadIdx.x & 63;
  const float* rmax = rowmax + (b << 10);
  const float* rinv = rowinv + (b << 10);
  int m0 = lane * 16;
  float rm[16], ri[16];
#pragma unroll
  for (int i = 0; i < 4; ++i) {
    float4 a = ((const float4*)(rmax + m0))[i];
    rm[i * 4 + 0] = a.x; rm[i * 4 + 1] = a.y; rm[i * 4 + 2] = a.z; rm[i * 4 + 3] = a.w;
    float4 c = ((const float4*)(rinv + m0))[i];
    ri[i * 4 + 0] = c.x; ri[i * 4 + 1] = c.y; ri[i * 4 + 2] = c.z; ri[i * 4 + 3] = c.w;
  }
  for (int rr = wave; rr < 64; rr += 4) {
    int np = np0 + rr;
    size_t rowoff = (size_t)(b * 4096 + np) << 10;
    const f16x8* src = (const f16x8*)(LT + rowoff + m0);
    f16x8 h0 = src[0], h1 = src[1];
    float v[16];
#pragma unroll
    for (int k = 0; k < 8; ++k) { v[k] = (float)h0[k]; v[8 + k] = (float)h1[k]; }
    float vm = v[0];
#pragma unroll
    for (int k = 1; k < 16; ++k) vm = fmaxf(vm, v[k]);
#pragma unroll
    for (int d = 1; d < 64; d <<= 1) vm = fmaxf(vm, __shfl_xor(vm, d));
    float csum = 0.f, cms = 0.f;
    union { short s[16]; int4 q4[2]; } pk;
#pragma unroll
    for (int k = 0; k < 16; ++k) {
      float e = __expf(v[k] - vm);
      csum += e;
      pk.s[k] = f2bf(e);
      cms += __expf(v[k] - rm[k]) * ri[k];
    }
#pragma unroll
    for (int d = 1; d < 64; d <<= 1) {
      csum += __shfl_xor(csum, d);
      cms += __shfl_xor(cms, d);
    }
    int4* dst = (int4*)(DwT + rowoff + m0);
    dst[0] = pk.q4[0];
    dst[1] = pk.q4[1];
    if (lane == 0) {
      colinv[(b << 12) + np] = 1.f / csum;
      Cm[(b << 12) + np] = cms * (1.f / 1024.f);
    }
  }
}

// ---------------- final combine ----------------

__global__ __launch_bounds__(512) void yinit(const float* __restrict__ Cm,
                                             const float* __restrict__ b2,
                                             float* __restrict__ Y) {
  __shared__ float s[8];
  int b = blockIdx.x;
  int w = threadIdx.x >> 6, l = threadIdx.x & 63;
  float acc = 0.f;
  for (int p = l; p < 512; p += 64) acc += Cm[(b * 8 + w) * 512 + p];
  for (int d = 32; d; d >>= 1) acc += __shfl_xor(acc, d);
  if (l == 0) s[w] = acc;
  __syncthreads();
  int o = threadIdx.x;
  float yv = 0.f;
#pragma unroll
  for (int n = 0; n < 8; ++n) yv += s[n] * b2[n * 512 + o];
  Y[b * 512 + o] = yv;
}

__global__ __launch_bounds__(256) void gw2(const float* __restrict__ G,
                                           const float* __restrict__ W2,
                                           float* __restrict__ Y) {
  int o = blockIdx.x * 256 + threadIdx.x;  // 0..511
  int k0 = blockIdx.y * 256;               // k = n*1024+h, 8192 total
  float acc[8] = {};
  for (int kk = 0; kk < 256; ++kk) {
    int k = k0 + kk;
    float w = W2[(size_t)k * 512 + o];
#pragma unroll
    for (int b = 0; b < 8; ++b) acc[b] += G[b * 8192 + k] * w;
  }
#pragma unroll
  for (int b = 0; b < 8; ++b) atomicAdd(&Y[b * 512 + o], acc[b]);
}

// ---------------- launch ----------------

extern "C" void kernel_launch(void* const* d_in, const int* in_sizes, int n_in,
                              void* d_out, int out_size, void* d_ws, size_t ws_size,
                              hipStream_t stream) {
  const float* x = (const float*)d_in[0];
  const float* phi = (const float*)d_in[1];
  const float* W1 = (const float*)d_in[2];
  const float* b1 = (const float*)d_in[3];
  const float* W2 = (const float*)d_in[4];
  const float* b2 = (const float*)d_in[5];
  float* Y = (float*)d_out;

  size_t off = 0;
  auto alloc = [&](size_t n) {
    void* p = (char*)d_ws + off;
    off += (n + 255) & ~(size_t)255;
    return p;
  };
  // Region A: LT fp16 [8][4096][1024]; Xs bf16 aliases it after rowpass.
  short* LT = (short*)alloc(8ull * 4096 * 1024 * 2);  // 67.1 MB
  short* Xs = LT;
  // Region B: DwT bf16 [8][4096][1024]; xh/pT live here before rowpass.
  short* DwT = (short*)alloc(8ull * 4096 * 1024 * 2);  // 67.1 MB
  short* xh = DwT;                                     // fp16 (dead after gemm0)
  short* pT = DwT + 8ull * 1024 * 1024;                // fp16 (dead after gemm0)
  short* xT = (short*)alloc(8ull * 1024 * 1024 * 2);   // bf16, live thru gemm1
  short* W1T = (short*)alloc(8ull * 1024 * 1024 * 2);  // bf16, live thru gemm2
  float* Pr = (float*)alloc(8ull * 1024 * 64 * 2 * 4); // 4 MB partials
  float* rowmaxv = (float*)alloc(8192 * 4);
  float* rowinvv = (float*)alloc(8192 * 4);
  float* colinvv = (float*)alloc(32768 * 4);
  float* CmB = (float*)alloc(32768 * 4);
  float* G = (float*)alloc(8ull * 8192 * 4);
  // peak off ~= 172 MiB

  conv_x<<<dim3(256, 8), 256, 0, stream>>>(x, xh, xT);
  conv_phi<<<dim3(1024), 256, 0, stream>>>(phi, pT);
  conv_w1<<<dim3(256, 8), 256, 0, stream>>>(W1, W1T);

  // LT = (xh * pT)^T fp16 + Cw partials
  gemm_k<0><<<dim3(256, 8), 256, 0, stream>>>(xh, pT, Pr, LT,
                                              nullptr, nullptr, nullptr, nullptr);
  rowfin<<<dim3(2048), 256, 0, stream>>>(Pr, rowmaxv, rowinvv);
  rowpass<<<dim3(64, 8), 256, 0, stream>>>(LT, rowmaxv, rowinvv, DwT, colinvv, CmB);

  // Xs = (DwT * xT) * colinv   (bf16 out; overwrites LT region)
  gemm_k<1><<<dim3(256, 8), 256, 0, stream>>>(DwT, xT, nullptr, Xs,
                                              colinvv, nullptr, nullptr, nullptr);

  zeroG<<<dim3(256), 256, 0, stream>>>(G);
  // G[b,n,h] = sum_p Cm * relu(Xs*W1T + b1)
  gemm_k<2><<<dim3(32, 64), 256, 0, stream>>>(Xs, W1T, nullptr, nullptr,
                                              nullptr, CmB, b1, G);

  yinit<<<dim3(8), 512, 0, stream>>>(CmB, b2, Y);
  gw2<<<dim3(2, 32), 256, 0, stream>>>(G, W2, Y);
}

// Round 5
// 350.915 us; speedup vs baseline: 2.2245x; 1.1826x over previous
//
#include <hip/hip_runtime.h>

// SoftMoe on MI355X (gfx950).
// R5: GEMM template upgraded from serial 2-barrier 128x128 to a pipelined
// 256x256 / BK=32 / 8-wave kernel: 4-deep LDS ring, depth-2 prefetch with
// counted s_waitcnt vmcnt(8) (loads in flight across barriers, T3+T4), one
// raw s_barrier per K-tile (provably race-free at wave skew <=1 with a
// 4-buffer ring), T2 both-sides bank-swizzle (pre-swizzled global source +
// swizzled ds_read; LDS dest stays linear for global_load_lds), setprio
// around the MFMA cluster (T5).
//
// Pipeline (unchanged from R4 outside the GEMMs):
//   conv_x / conv_phi / conv_w1 -> fp16/bf16 operands (+ transposes)
//   gemm<0>: LT fp16 [b][np][m] = (xh*pT)^T + Cw row-softmax partials Pr
//   rowfin:  merge Pr -> rowmax/rowinv
//   rowpass: DwT bf16 = exp(l-colmax) (unnorm), colinv, Cm  (contiguous rows)
//   gemm<1>: Xs bf16 = (DwT * xT) * colinv
//   gemm<2>: relu(Xs*W1T+b1) contracted with Cm over p -> atomicAdd G
//   yinit + gw2: Y = G.W2 + (sum_p Cm).b2
//
// Workspace (liveness-aliased, peak ~172 MiB): see launch().

#define DI __device__ __forceinline__

typedef __attribute__((ext_vector_type(8))) __bf16 bf16x8;
typedef __attribute__((ext_vector_type(8))) _Float16 f16x8;
typedef __attribute__((ext_vector_type(4))) float f32x4;

DI short f2bf(float v) {
  union { float f; unsigned u; } a; a.f = v;
  unsigned u = a.u;
  unsigned r = (u + 0x7FFFu + ((u >> 16) & 1u)) >> 16;  // RNE
  return (short)r;
}
DI short f2h(float v) {
  union { _Float16 h[2]; short s[2]; } a;
  a.h[0] = (_Float16)v;  // RNE
  return a.s[0];
}

DI void gload_lds16(const void* g, void* l) {
  __builtin_amdgcn_global_load_lds(
      (__attribute__((address_space(1))) unsigned int*)g,
      (__attribute__((address_space(3))) unsigned int*)l, 16, 0, 0);
}

// ---------------- conversion kernels ----------------

__global__ __launch_bounds__(256) void conv_x(const float* __restrict__ x,
                                              short* __restrict__ xh,
                                              short* __restrict__ xT) {
  __shared__ short t0[64][66];
  int b = blockIdx.y;
  int mt = (blockIdx.x >> 4) * 64;
  int dt = (blockIdx.x & 15) * 64;
  int c = threadIdx.x & 63, r0 = threadIdx.x >> 6;
  size_t base = (size_t)b << 20;
#pragma unroll
  for (int i = 0; i < 16; ++i) {
    int r = r0 + i * 4;
    size_t idx = base + (size_t)(mt + r) * 1024 + dt + c;
    float v = x[idx];
    xh[idx] = f2h(v);
    t0[r][c] = f2bf(v);
  }
  __syncthreads();
#pragma unroll
  for (int i = 0; i < 16; ++i) {
    int u = r0 + i * 4;
    xT[base + (size_t)(dt + u) * 1024 + mt + c] = t0[c][u];
  }
}

__global__ __launch_bounds__(256) void conv_phi(const float* __restrict__ phi,
                                                short* __restrict__ pT) {
  __shared__ short th[64][66];
  int dt = (blockIdx.x >> 6) * 64;
  int pt = (blockIdx.x & 63) * 64;
  int c = threadIdx.x & 63, r0 = threadIdx.x >> 6;
#pragma unroll
  for (int i = 0; i < 16; ++i) {
    int r = r0 + i * 4;
    th[r][c] = f2h(phi[(size_t)(dt + r) * 4096 + pt + c]);
  }
  __syncthreads();
#pragma unroll
  for (int i = 0; i < 16; ++i) {
    int u = r0 + i * 4;
    pT[(size_t)(pt + u) * 1024 + dt + c] = th[c][u];
  }
}

__global__ __launch_bounds__(256) void conv_w1(const float* __restrict__ W1,
                                               short* __restrict__ W1T) {
  __shared__ short t0[64][66];
  int n = blockIdx.y;
  int dt = (blockIdx.x >> 4) * 64;
  int ht = (blockIdx.x & 15) * 64;
  int c = threadIdx.x & 63, r0 = threadIdx.x >> 6;
  size_t base = (size_t)n << 20;
#pragma unroll
  for (int i = 0; i < 16; ++i) {
    int r = r0 + i * 4;
    t0[r][c] = f2bf(W1[base + (size_t)(dt + r) * 1024 + ht + c]);
  }
  __syncthreads();
#pragma unroll
  for (int i = 0; i < 16; ++i) {
    int u = r0 + i * 4;
    W1T[base + (size_t)(ht + u) * 1024 + dt + c] = t0[c][u];
  }
}

__global__ __launch_bounds__(256) void zeroG(float* __restrict__ G) {
  G[blockIdx.x * 256 + threadIdx.x] = 0.f;
}

// ------------- pipelined GEMM (256x256, BK=32, 8 waves, 4-buf ring) --------
// EPI 0: LT fp16 transposed out + Cw row-softmax partials (fp16 MFMA)
// EPI 1: Xs bf16 out, per-row scale colinv (bf16 MFMA)
// EPI 2: relu(+b1), Cm-weighted column sums -> atomicAdd G (bf16 MFMA)
// K = 1024 for all (NT = 32 K-tiles of 32).

template <int EPI>
__global__ __launch_bounds__(512, 2) void gemm_k(
    const short* __restrict__ A0, const short* __restrict__ B0,
    float* __restrict__ Cf, short* __restrict__ Cbs,
    const float* __restrict__ rowScale, const float* __restrict__ rowW,
    const float* __restrict__ colBias, float* __restrict__ G) {
  constexpr int TN = (EPI == 0) ? 16 : 4;
  constexpr size_t ASTR = (EPI == 0) ? (1u << 20) : (EPI == 1 ? (1u << 22) : (1u << 19));
  constexpr size_t BSTR = (EPI == 0) ? 0 : (1u << 20);
  constexpr int BMASK = (EPI == 2) ? 7 : 0xFFFF;
  constexpr int NT = 32;

  __shared__ short lds[65536];  // 4 bufs x (A 8192 + B 8192 shorts) = 128 KiB

  int y = blockIdx.y;
  int bx = blockIdx.x;
  int brow = (bx / TN) * 256;
  int bcol = (bx % TN) * 256;
  int t = threadIdx.x, lane = t & 63, wid = t >> 6;
  int wm = wid >> 2, wn = wid & 3;  // 2 x 4 wave grid; per-wave C = 128 x 64

  const short* Abase = A0 + (size_t)y * ASTR + (size_t)brow * 1024;
  const short* Bbase = B0 + (size_t)(y & BMASK) * BSTR + (size_t)bcol * 1024;

  f32x4 acc[8][4] = {};

  // staging: linear LDS dest (global_load_lds needs wave-uniform base+lane*16),
  // bank-swizzle applied by pre-swizzling the GLOBAL k-offset (involution):
  //   k_slot ^= (row>>1)&3   (16B slots within the 64B row)
  int sr = t >> 2;                               // tile row, round 0 (round 1: +128)
  int ske = (((t & 3) ^ ((sr >> 1) & 3)) << 3);  // swizzled source k (elements)
  const size_t sroff0 = (size_t)sr * 1024 + ske;
  const size_t sroff1 = (size_t)(sr + 128) * 1024 + ske;  // (sr+128)>>1 & 3 == (sr>>1)&3

  auto stage = [&](int kt) {
    short* lb = lds + (kt & 3) * 16384;
    const short* gA = Abase + kt * 32;
    const short* gB = Bbase + kt * 32;
    gload_lds16(gA + sroff0, lb + t * 8);
    gload_lds16(gA + sroff1, lb + 4096 + t * 8);
    gload_lds16(gB + sroff0, lb + 8192 + t * 8);
    gload_lds16(gB + sroff1, lb + 12288 + t * 8);
  };

  int fr = lane & 15;
  // swizzled read slot: same involution; (row>>1)&3 == (fr>>1)&3 for all frags
  int slotE = (((lane >> 4) ^ ((fr >> 1) & 3)) << 3);

  stage(0);
  stage(1);

  for (int kt = 0; kt < NT; ++kt) {
    if (kt + 2 < NT) stage(kt + 2);
    // counted vmcnt: allow the 8 loads of tiles kt+1,kt+2 to stay in flight;
    // in-order retirement => tile kt has landed for THIS wave.
    if (kt < NT - 2) {
      asm volatile("s_waitcnt vmcnt(8)" ::: "memory");
    } else if (kt == NT - 2) {
      asm volatile("s_waitcnt vmcnt(4)" ::: "memory");
    } else {
      asm volatile("s_waitcnt vmcnt(0)" ::: "memory");
    }
    asm volatile("" ::: "memory");
    __builtin_amdgcn_s_barrier();  // all waves' tile-kt portions visible
    asm volatile("" ::: "memory");

    const short* lA = lds + (kt & 3) * 16384;
    const short* lB = lA + 8192;
    if constexpr (EPI == 0) {
      f16x8 a[8], b[4];
#pragma unroll
      for (int i = 0; i < 8; ++i)
        a[i] = *(const f16x8*)(lA + (wm * 128 + i * 16 + fr) * 32 + slotE);
#pragma unroll
      for (int j = 0; j < 4; ++j)
        b[j] = *(const f16x8*)(lB + (wn * 64 + j * 16 + fr) * 32 + slotE);
      __builtin_amdgcn_s_setprio(1);
#pragma unroll
      for (int i = 0; i < 8; ++i)
#pragma unroll
        for (int j = 0; j < 4; ++j)
          acc[i][j] = __builtin_amdgcn_mfma_f32_16x16x32_f16(a[i], b[j], acc[i][j], 0, 0, 0);
      __builtin_amdgcn_s_setprio(0);
    } else {
      bf16x8 a[8], b[4];
#pragma unroll
      for (int i = 0; i < 8; ++i)
        a[i] = *(const bf16x8*)(lA + (wm * 128 + i * 16 + fr) * 32 + slotE);
#pragma unroll
      for (int j = 0; j < 4; ++j)
        b[j] = *(const bf16x8*)(lB + (wn * 64 + j * 16 + fr) * 32 + slotE);
      __builtin_amdgcn_s_setprio(1);
#pragma unroll
      for (int i = 0; i < 8; ++i)
#pragma unroll
        for (int j = 0; j < 4; ++j)
          acc[i][j] = __builtin_amdgcn_mfma_f32_16x16x32_bf16(a[i], b[j], acc[i][j], 0, 0, 0);
      __builtin_amdgcn_s_setprio(0);
    }
  }

  int fc = lane & 15, fq = (lane >> 4) * 4;

  if constexpr (EPI == 0) {
    // transposed fp16 write LT[np][m] + Cw row partials
    short* LT = Cbs + ((size_t)y << 22);
#pragma unroll
    for (int i = 0; i < 8; ++i) {
      int r0 = brow + wm * 128 + i * 16 + fq;
#pragma unroll
      for (int j = 0; j < 4; ++j) {
        int c = bcol + wn * 64 + j * 16 + fc;
        union { short s[4]; int2 v2; } pk;
#pragma unroll
        for (int q = 0; q < 4; ++q) pk.s[q] = f2h(acc[i][j][q]);
        *(int2*)(LT + ((size_t)c << 10) + r0) = pk.v2;
      }
    }
    float* Pr = Cf + ((size_t)y << 17);  // [1024 m][64 chunks] float2
    int chunk = (bcol >> 6) + wn;        // this wave's 64-np chunk
#pragma unroll
    for (int i = 0; i < 8; ++i) {
#pragma unroll
      for (int q = 0; q < 4; ++q) {
        float vm = fmaxf(fmaxf(acc[i][0][q], acc[i][1][q]),
                         fmaxf(acc[i][2][q], acc[i][3][q]));
#pragma unroll
        for (int d = 1; d < 16; d <<= 1) vm = fmaxf(vm, __shfl_xor(vm, d));
        float s = 0.f;
#pragma unroll
        for (int j = 0; j < 4; ++j) s += __expf(acc[i][j][q] - vm);
#pragma unroll
        for (int d = 1; d < 16; d <<= 1) s += __shfl_xor(s, d);
        if (fc == 0) {
          int m = brow + wm * 128 + i * 16 + fq + q;
          *(float2*)(Pr + ((size_t)m * 64 + chunk) * 2) = make_float2(vm, s);
        }
      }
    }
  } else if constexpr (EPI == 1) {
    short* C = Cbs + ((size_t)y << 22);
    const float* rs = rowScale + ((size_t)y << 12);
#pragma unroll
    for (int i = 0; i < 8; ++i) {
      int r = brow + wm * 128 + i * 16 + fq;
#pragma unroll
      for (int j = 0; j < 4; ++j) {
        int c = bcol + wn * 64 + j * 16 + fc;
#pragma unroll
        for (int q = 0; q < 4; ++q)
          C[(size_t)(r + q) * 1024 + c] = f2bf(acc[i][j][q] * rs[r + q]);
      }
    }
  } else {
    const float* cmv = rowW + ((size_t)y << 9);          // Cm slab (512 p-rows)
    const float* bb = colBias + ((size_t)(y & 7) << 10); // b1[n]
    float* g = G + ((size_t)y << 10);
#pragma unroll
    for (int j = 0; j < 4; ++j) {
      int c = bcol + wn * 64 + j * 16 + fc;  // h
      float bias = bb[c];
      float sum = 0.f;
#pragma unroll
      for (int i = 0; i < 8; ++i) {
        int r = brow + wm * 128 + i * 16 + fq;  // p
#pragma unroll
        for (int q = 0; q < 4; ++q) {
          float h = acc[i][j][q] + bias;
          h = fmaxf(h, 0.f);
          sum += cmv[r + q] * h;
        }
      }
      sum += __shfl_xor(sum, 16);
      sum += __shfl_xor(sum, 32);
      if (fq == 0) atomicAdd(&g[c], sum);
    }
  }
}

// ---------------- softmax stage ----------------

__global__ __launch_bounds__(256) void rowfin(const float* __restrict__ Pr,
                                              float* __restrict__ rowmax,
                                              float* __restrict__ rowinv) {
  int row = blockIdx.x * 4 + (threadIdx.x >> 6);  // global b*1024+m
  int lane = threadIdx.x & 63;
  float2 p = ((const float2*)Pr)[(size_t)row * 64 + lane];
  float vm = p.x;
#pragma unroll
  for (int d = 1; d < 64; d <<= 1) vm = fmaxf(vm, __shfl_xor(vm, d));
  float s = p.y * __expf(p.x - vm);
#pragma unroll
  for (int d = 1; d < 64; d <<= 1) s += __shfl_xor(s, d);
  if (lane == 0) {
    rowmax[row] = vm;
    rowinv[row] = 1.f / s;
  }
}

__global__ __launch_bounds__(256) void rowpass(const short* __restrict__ LT,
                                               const float* __restrict__ rowmax,
                                               const float* __restrict__ rowinv,
                                               short* __restrict__ DwT,
                                               float* __restrict__ colinv,
                                               float* __restrict__ Cm) {
  int b = blockIdx.y;
  int np0 = blockIdx.x * 64;
  int wave = threadIdx.x >> 6, lane = threadIdx.x & 63;
  const float* rmax = rowmax + (b << 10);
  const float* rinv = rowinv + (b << 10);
  int m0 = lane * 16;
  float rm[16], ri[16];
#pragma unroll
  for (int i = 0; i < 4; ++i) {
    float4 a = ((const float4*)(rmax + m0))[i];
    rm[i * 4 + 0] = a.x; rm[i * 4 + 1] = a.y; rm[i * 4 + 2] = a.z; rm[i * 4 + 3] = a.w;
    float4 c = ((const float4*)(rinv + m0))[i];
    ri[i * 4 + 0] = c.x; ri[i * 4 + 1] = c.y; ri[i * 4 + 2] = c.z; ri[i * 4 + 3] = c.w;
  }
  for (int rr = wave; rr < 64; rr += 4) {
    int np = np0 + rr;
    size_t rowoff = (size_t)(b * 4096 + np) << 10;
    const f16x8* src = (const f16x8*)(LT + rowoff + m0);
    f16x8 h0 = src[0], h1 = src[1];
    float v[16];
#pragma unroll
    for (int k = 0; k < 8; ++k) { v[k] = (float)h0[k]; v[8 + k] = (float)h1[k]; }
    float vm = v[0];
#pragma unroll
    for (int k = 1; k < 16; ++k) vm = fmaxf(vm, v[k]);
#pragma unroll
    for (int d = 1; d < 64; d <<= 1) vm = fmaxf(vm, __shfl_xor(vm, d));
    float csum = 0.f, cms = 0.f;
    union { short s[16]; int4 q4[2]; } pk;
#pragma unroll
    for (int k = 0; k < 16; ++k) {
      float e = __expf(v[k] - vm);
      csum += e;
      pk.s[k] = f2bf(e);
      cms += __expf(v[k] - rm[k]) * ri[k];
    }
#pragma unroll
    for (int d = 1; d < 64; d <<= 1) {
      csum += __shfl_xor(csum, d);
      cms += __shfl_xor(cms, d);
    }
    int4* dst = (int4*)(DwT + rowoff + m0);
    dst[0] = pk.q4[0];
    dst[1] = pk.q4[1];
    if (lane == 0) {
      colinv[(b << 12) + np] = 1.f / csum;
      Cm[(b << 12) + np] = cms * (1.f / 1024.f);
    }
  }
}

// ---------------- final combine ----------------

__global__ __launch_bounds__(512) void yinit(const float* __restrict__ Cm,
                                             const float* __restrict__ b2,
                                             float* __restrict__ Y) {
  __shared__ float s[8];
  int b = blockIdx.x;
  int w = threadIdx.x >> 6, l = threadIdx.x & 63;
  float acc = 0.f;
  for (int p = l; p < 512; p += 64) acc += Cm[(b * 8 + w) * 512 + p];
  for (int d = 32; d; d >>= 1) acc += __shfl_xor(acc, d);
  if (l == 0) s[w] = acc;
  __syncthreads();
  int o = threadIdx.x;
  float yv = 0.f;
#pragma unroll
  for (int n = 0; n < 8; ++n) yv += s[n] * b2[n * 512 + o];
  Y[b * 512 + o] = yv;
}

__global__ __launch_bounds__(256) void gw2(const float* __restrict__ G,
                                           const float* __restrict__ W2,
                                           float* __restrict__ Y) {
  int o = blockIdx.x * 256 + threadIdx.x;  // 0..511
  int k0 = blockIdx.y * 256;               // k = n*1024+h, 8192 total
  float acc[8] = {};
  for (int kk = 0; kk < 256; ++kk) {
    int k = k0 + kk;
    float w = W2[(size_t)k * 512 + o];
#pragma unroll
    for (int b = 0; b < 8; ++b) acc[b] += G[b * 8192 + k] * w;
  }
#pragma unroll
  for (int b = 0; b < 8; ++b) atomicAdd(&Y[b * 512 + o], acc[b]);
}

// ---------------- launch ----------------

extern "C" void kernel_launch(void* const* d_in, const int* in_sizes, int n_in,
                              void* d_out, int out_size, void* d_ws, size_t ws_size,
                              hipStream_t stream) {
  const float* x = (const float*)d_in[0];
  const float* phi = (const float*)d_in[1];
  const float* W1 = (const float*)d_in[2];
  const float* b1 = (const float*)d_in[3];
  const float* W2 = (const float*)d_in[4];
  const float* b2 = (const float*)d_in[5];
  float* Y = (float*)d_out;

  size_t off = 0;
  auto alloc = [&](size_t n) {
    void* p = (char*)d_ws + off;
    off += (n + 255) & ~(size_t)255;
    return p;
  };
  // Region A: LT fp16 [8][4096][1024]; Xs bf16 aliases it after rowpass.
  short* LT = (short*)alloc(8ull * 4096 * 1024 * 2);  // 67.1 MB
  short* Xs = LT;
  // Region B: DwT bf16 [8][4096][1024]; xh/pT live here before rowpass.
  short* DwT = (short*)alloc(8ull * 4096 * 1024 * 2);  // 67.1 MB
  short* xh = DwT;                                     // fp16 (dead after gemm0)
  short* pT = DwT + 8ull * 1024 * 1024;                // fp16 (dead after gemm0)
  short* xT = (short*)alloc(8ull * 1024 * 1024 * 2);   // bf16, live thru gemm1
  short* W1T = (short*)alloc(8ull * 1024 * 1024 * 2);  // bf16, live thru gemm2
  float* Pr = (float*)alloc(8ull * 1024 * 64 * 2 * 4); // 4 MB partials
  float* rowmaxv = (float*)alloc(8192 * 4);
  float* rowinvv = (float*)alloc(8192 * 4);
  float* colinvv = (float*)alloc(32768 * 4);
  float* CmB = (float*)alloc(32768 * 4);
  float* G = (float*)alloc(8ull * 8192 * 4);
  // peak off ~= 172 MiB

  conv_x<<<dim3(256, 8), 256, 0, stream>>>(x, xh, xT);
  conv_phi<<<dim3(1024), 256, 0, stream>>>(phi, pT);
  conv_w1<<<dim3(256, 8), 256, 0, stream>>>(W1, W1T);

  // LT = (xh * pT)^T fp16 + Cw partials.  M=1024,N=4096 -> 4x16 tiles
  gemm_k<0><<<dim3(64, 8), 512, 0, stream>>>(xh, pT, Pr, LT,
                                             nullptr, nullptr, nullptr, nullptr);
  rowfin<<<dim3(2048), 256, 0, stream>>>(Pr, rowmaxv, rowinvv);
  rowpass<<<dim3(64, 8), 256, 0, stream>>>(LT, rowmaxv, rowinvv, DwT, colinvv, CmB);

  // Xs = (DwT * xT) * colinv.  M=4096,N=1024 -> 16x4 tiles
  gemm_k<1><<<dim3(64, 8), 512, 0, stream>>>(DwT, xT, nullptr, Xs,
                                             colinvv, nullptr, nullptr, nullptr);

  zeroG<<<dim3(256), 256, 0, stream>>>(G);
  // G[b,n,h] = sum_p Cm * relu(Xs*W1T + b1).  M=512,N=1024 -> 2x4 tiles, y=(b,n)
  gemm_k<2><<<dim3(8, 64), 512, 0, stream>>>(Xs, W1T, nullptr, nullptr,
                                             nullptr, CmB, b1, G);

  yinit<<<dim3(8), 512, 0, stream>>>(CmB, b2, Y);
  gw2<<<dim3(2, 32), 256, 0, stream>>>(G, W2, Y);
}

// Round 6
// 341.332 us; speedup vs baseline: 2.2870x; 1.0281x over previous
//
#include <hip/hip_runtime.h>

// SoftMoe on MI355X (gfx950).
// R6: GEMM rewritten to the 256x256 / BK=64 / 8-wave 4-phase schedule
// (m201-style): per K-tile 4 phases of {stage-half || ds_read next quadrant
// || 16 MFMA current quadrant} + 1 barrier; one counted vmcnt(4) per tile.
// LDS: 2 bufs x 64KB (tile T in buf T&1); staging T+2 overwrites only
// regions dead since >=1 barrier (B dead after ph1 -> staged at ph2; A dead
// after ph2 -> staged at ph3). 8-slot XOR swizzle (slot ^= row&7) applied
// both-sides: pre-swizzled global source, swizzled ds_read.
//
// Pipeline (unchanged outside the GEMMs):
//   conv_x / conv_phi / conv_w1 -> fp16/bf16 operands (+ transposes)
//   gemm<0>: LT fp16 [b][np][m] = (xh*pT)^T + Cw row-softmax partials Pr
//   rowfin:  merge Pr -> rowmax/rowinv
//   rowpass: DwT bf16 = exp(l-colmax) (unnorm), colinv, Cm
//   gemm<1>: Xs bf16 = (DwT * xT) * colinv
//   gemm<2>: relu(Xs*W1T+b1) contracted with Cm over p -> atomicAdd G
//   yinit + gw2: Y = G.W2 + (sum_p Cm).b2

#define DI __device__ __forceinline__

typedef __attribute__((ext_vector_type(8))) __bf16 bf16x8;
typedef __attribute__((ext_vector_type(8))) _Float16 f16x8;
typedef __attribute__((ext_vector_type(8))) short s16x8;
typedef __attribute__((ext_vector_type(4))) float f32x4;

DI short f2bf(float v) {
  union { float f; unsigned u; } a; a.f = v;
  unsigned u = a.u;
  unsigned r = (u + 0x7FFFu + ((u >> 16) & 1u)) >> 16;  // RNE
  return (short)r;
}
DI short f2h(float v) {
  union { _Float16 h[2]; short s[2]; } a;
  a.h[0] = (_Float16)v;  // RNE
  return a.s[0];
}

DI void gload_lds16(const void* g, void* l) {
  __builtin_amdgcn_global_load_lds(
      (__attribute__((address_space(1))) unsigned int*)g,
      (__attribute__((address_space(3))) unsigned int*)l, 16, 0, 0);
}

template <int EPI>
DI f32x4 mfop(s16x8 a, s16x8 b, f32x4 c) {
  if constexpr (EPI == 0)
    return __builtin_amdgcn_mfma_f32_16x16x32_f16(
        __builtin_bit_cast(f16x8, a), __builtin_bit_cast(f16x8, b), c, 0, 0, 0);
  else
    return __builtin_amdgcn_mfma_f32_16x16x32_bf16(
        __builtin_bit_cast(bf16x8, a), __builtin_bit_cast(bf16x8, b), c, 0, 0, 0);
}

// ---------------- conversion kernels ----------------

__global__ __launch_bounds__(256) void conv_x(const float* __restrict__ x,
                                              short* __restrict__ xh,
                                              short* __restrict__ xT) {
  __shared__ short t0[64][66];
  int b = blockIdx.y;
  int mt = (blockIdx.x >> 4) * 64;
  int dt = (blockIdx.x & 15) * 64;
  int c = threadIdx.x & 63, r0 = threadIdx.x >> 6;
  size_t base = (size_t)b << 20;
#pragma unroll
  for (int i = 0; i < 16; ++i) {
    int r = r0 + i * 4;
    size_t idx = base + (size_t)(mt + r) * 1024 + dt + c;
    float v = x[idx];
    xh[idx] = f2h(v);
    t0[r][c] = f2bf(v);
  }
  __syncthreads();
#pragma unroll
  for (int i = 0; i < 16; ++i) {
    int u = r0 + i * 4;
    xT[base + (size_t)(dt + u) * 1024 + mt + c] = t0[c][u];
  }
}

__global__ __launch_bounds__(256) void conv_phi(const float* __restrict__ phi,
                                                short* __restrict__ pT) {
  __shared__ short th[64][66];
  int dt = (blockIdx.x >> 6) * 64;
  int pt = (blockIdx.x & 63) * 64;
  int c = threadIdx.x & 63, r0 = threadIdx.x >> 6;
#pragma unroll
  for (int i = 0; i < 16; ++i) {
    int r = r0 + i * 4;
    th[r][c] = f2h(phi[(size_t)(dt + r) * 4096 + pt + c]);
  }
  __syncthreads();
#pragma unroll
  for (int i = 0; i < 16; ++i) {
    int u = r0 + i * 4;
    pT[(size_t)(pt + u) * 1024 + dt + c] = th[c][u];
  }
}

__global__ __launch_bounds__(256) void conv_w1(const float* __restrict__ W1,
                                               short* __restrict__ W1T) {
  __shared__ short t0[64][66];
  int n = blockIdx.y;
  int dt = (blockIdx.x >> 4) * 64;
  int ht = (blockIdx.x & 15) * 64;
  int c = threadIdx.x & 63, r0 = threadIdx.x >> 6;
  size_t base = (size_t)n << 20;
#pragma unroll
  for (int i = 0; i < 16; ++i) {
    int r = r0 + i * 4;
    t0[r][c] = f2bf(W1[base + (size_t)(dt + r) * 1024 + ht + c]);
  }
  __syncthreads();
#pragma unroll
  for (int i = 0; i < 16; ++i) {
    int u = r0 + i * 4;
    W1T[base + (size_t)(ht + u) * 1024 + dt + c] = t0[c][u];
  }
}

__global__ __launch_bounds__(256) void zeroG(float* __restrict__ G) {
  G[blockIdx.x * 256 + threadIdx.x] = 0.f;
}

// ---- pipelined GEMM: 256x256, BK=64, 8 waves, 2-buf dbuf, 4 phases/tile ----
// EPI 0: LT fp16 transposed out + Cw row-softmax partials (fp16 MFMA)
// EPI 1: Xs bf16 out, per-row scale colinv (bf16 MFMA)
// EPI 2: relu(+b1), Cm-weighted column sums -> atomicAdd G (bf16 MFMA)
// K = 1024 for all: NT = 16 K-tiles of 64.

#define BAR()                         \
  asm volatile("" ::: "memory");      \
  __builtin_amdgcn_s_barrier();       \
  asm volatile("" ::: "memory")

#define MFMA16(AB, AV, BV)                                                 \
  __builtin_amdgcn_s_setprio(1);                                           \
  _Pragma("unroll") for (int fi = 0; fi < 4; ++fi)                         \
      _Pragma("unroll") for (int fj = 0; fj < 4; ++fj)                     \
          acc[AB + fi][fj] = mfop<EPI>(AV[fi], BV[fj], acc[AB + fi][fj]);  \
  __builtin_amdgcn_s_setprio(0)

template <int EPI>
__global__ __launch_bounds__(512, 2) void gemm_k(
    const short* __restrict__ A0, const short* __restrict__ B0,
    float* __restrict__ Cf, short* __restrict__ Cbs,
    const float* __restrict__ rowScale, const float* __restrict__ rowW,
    const float* __restrict__ colBias, float* __restrict__ G) {
  constexpr int TN = (EPI == 0) ? 16 : 4;
  constexpr size_t ASTR = (EPI == 0) ? (1u << 20) : (EPI == 1 ? (1u << 22) : (1u << 19));
  constexpr size_t BSTR = (EPI == 0) ? 0 : (1u << 20);
  constexpr int BMASK = (EPI == 2) ? 7 : 0xFFFF;
  constexpr int NT = 16;

  __shared__ short lds[65536];  // 2 bufs x (A 256x64 + B 256x64) shorts = 128 KiB

  int y = blockIdx.y;
  int bx = blockIdx.x;
  int brow = (bx / TN) * 256;
  int bcol = (bx % TN) * 256;
  int t = threadIdx.x, lane = t & 63, wid = t >> 6;
  int wm = wid >> 2, wn = wid & 3;  // 2 x 4 wave grid; per-wave C = 128 x 64
  int fr = lane & 15, fs = lane >> 4;

  const short* Abase = A0 + (size_t)y * ASTR + (size_t)brow * 1024;
  const short* Bbase = B0 + (size_t)(y & BMASK) * BSTR + (size_t)bcol * 1024;

  f32x4 acc[8][4] = {};

  // staging geometry: thread t covers (row = t>>3, 16B-slot = t&7) of a
  // 64-row round; source k pre-swizzled by (slot ^ (row&7)) so linear LDS
  // dest holds the swizzled layout.
  int rloc = t >> 3, cc = t & 7;
  size_t srcoff = (size_t)rloc * 1024 + (size_t)((cc ^ (rloc & 7)) << 3);

  auto stageOp = [&](const short* gbase, int T, int ldsbase) {
    short* dst = lds + (T & 1) * 32768 + ldsbase + t * 8;
    const short* src = gbase + T * 64 + srcoff;
#pragma unroll
    for (int h = 0; h < 2; ++h)
#pragma unroll
      for (int w = 0; w < 2; ++w)
        gload_lds16(src + (size_t)(h * 128 + w * 64) * 1024,
                    dst + h * 8192 + w * 4096);
  };

  // frag-read addressing (element units); slot swizzle is the same involution
  int e0 = fs ^ (fr & 7);        // k-subtile 0 slots 0..3
  int e1 = (4 + fs) ^ (fr & 7);  // k-subtile 1 slots 4..7
  int aoff = (wm * 128 + fr) * 64;
  int boff = 16384 + (wn * 64 + fr) * 64;

  auto LDA = [&](int d, int i, int ks) -> s16x8 {
    return *(const s16x8*)(lds + d * 32768 + aoff + i * 1024 + (ks ? e1 : e0) * 8);
  };
  auto LDB = [&](int d, int j, int ks) -> s16x8 {
    return *(const s16x8*)(lds + d * 32768 + boff + j * 1024 + (ks ? e1 : e0) * 8);
  };

  s16x8 aA[4], aB[4], bK0[4], bK1[4];

  // prologue: stage tiles 0,1 (B then A each); wait tile 0; preload ph0 frags
  stageOp(Bbase, 0, 16384);
  stageOp(Abase, 0, 0);
  stageOp(Bbase, 1, 16384);
  stageOp(Abase, 1, 0);
  asm volatile("s_waitcnt vmcnt(8)" ::: "memory");
  BAR();
#pragma unroll
  for (int i = 0; i < 4; ++i) aA[i] = LDA(0, i, 0);
#pragma unroll
  for (int j = 0; j < 4; ++j) bK0[j] = LDB(0, j, 0);

  for (int T = 0; T < NT; ++T) {
    int d = T & 1;
    // ---- ph0: read a[r1]ks0; MFMA (ks0, rows 0-3) ----
#pragma unroll
    for (int i = 0; i < 4; ++i) aB[i] = LDA(d, 4 + i, 0);
    MFMA16(0, aA, bK0);
    BAR();
    // ---- ph1: read a[r0]ks1 + b ks1; MFMA (ks0, rows 4-7) ----
#pragma unroll
    for (int i = 0; i < 4; ++i) aA[i] = LDA(d, i, 1);
#pragma unroll
    for (int j = 0; j < 4; ++j) bK1[j] = LDB(d, j, 1);
    MFMA16(4, aB, bK0);
    BAR();
    // ---- ph2: stage B(T+2) (B(T) dead since ph1); read a[r1]ks1;
    //           MFMA (ks1, rows 0-3); vmcnt(4) -> tile T+1 landed ----
    if (T + 2 < NT) stageOp(Bbase, T + 2, 16384);
#pragma unroll
    for (int i = 0; i < 4; ++i) aB[i] = LDA(d, 4 + i, 1);
    MFMA16(0, aA, bK1);
    if (T + 2 < NT) {
      asm volatile("s_waitcnt vmcnt(4)" ::: "memory");
    } else {
      asm volatile("s_waitcnt vmcnt(0)" ::: "memory");
    }
    BAR();
    // ---- ph3: stage A(T+2) (A(T) dead since ph2); read-ahead tile T+1
    //           (a[r0]ks0 + b ks0); MFMA (ks1, rows 4-7) ----
    if (T + 2 < NT) stageOp(Abase, T + 2, 0);
    if (T + 1 < NT) {
#pragma unroll
      for (int i = 0; i < 4; ++i) aA[i] = LDA(d ^ 1, i, 0);
#pragma unroll
      for (int j = 0; j < 4; ++j) bK0[j] = LDB(d ^ 1, j, 0);
    }
    MFMA16(4, aB, bK1);
    BAR();
  }

  int fc = lane & 15, fq = (lane >> 4) * 4;

  if constexpr (EPI == 0) {
    // transposed fp16 write LT[np][m] + Cw row partials
    short* LT = Cbs + ((size_t)y << 22);
#pragma unroll
    for (int i = 0; i < 8; ++i) {
      int r0 = brow + wm * 128 + i * 16 + fq;
#pragma unroll
      for (int j = 0; j < 4; ++j) {
        int c = bcol + wn * 64 + j * 16 + fc;
        union { short s[4]; int2 v2; } pk;
#pragma unroll
        for (int q = 0; q < 4; ++q) pk.s[q] = f2h(acc[i][j][q]);
        *(int2*)(LT + ((size_t)c << 10) + r0) = pk.v2;
      }
    }
    float* Pr = Cf + ((size_t)y << 17);  // [1024 m][64 chunks] float2
    int chunk = (bcol >> 6) + wn;
#pragma unroll
    for (int i = 0; i < 8; ++i) {
#pragma unroll
      for (int q = 0; q < 4; ++q) {
        float vm = fmaxf(fmaxf(acc[i][0][q], acc[i][1][q]),
                         fmaxf(acc[i][2][q], acc[i][3][q]));
#pragma unroll
        for (int d = 1; d < 16; d <<= 1) vm = fmaxf(vm, __shfl_xor(vm, d));
        float s = 0.f;
#pragma unroll
        for (int j = 0; j < 4; ++j) s += __expf(acc[i][j][q] - vm);
#pragma unroll
        for (int d = 1; d < 16; d <<= 1) s += __shfl_xor(s, d);
        if (fc == 0) {
          int m = brow + wm * 128 + i * 16 + fq + q;
          *(float2*)(Pr + ((size_t)m * 64 + chunk) * 2) = make_float2(vm, s);
        }
      }
    }
  } else if constexpr (EPI == 1) {
    short* C = Cbs + ((size_t)y << 22);
    const float* rs = rowScale + ((size_t)y << 12);
#pragma unroll
    for (int i = 0; i < 8; ++i) {
      int r = brow + wm * 128 + i * 16 + fq;
#pragma unroll
      for (int j = 0; j < 4; ++j) {
        int c = bcol + wn * 64 + j * 16 + fc;
#pragma unroll
        for (int q = 0; q < 4; ++q)
          C[(size_t)(r + q) * 1024 + c] = f2bf(acc[i][j][q] * rs[r + q]);
      }
    }
  } else {
    const float* cmv = rowW + ((size_t)y << 9);          // Cm slab (512 p-rows)
    const float* bb = colBias + ((size_t)(y & 7) << 10); // b1[n]
    float* g = G + ((size_t)y << 10);
#pragma unroll
    for (int j = 0; j < 4; ++j) {
      int c = bcol + wn * 64 + j * 16 + fc;  // h
      float bias = bb[c];
      float sum = 0.f;
#pragma unroll
      for (int i = 0; i < 8; ++i) {
        int r = brow + wm * 128 + i * 16 + fq;  // p
#pragma unroll
        for (int q = 0; q < 4; ++q) {
          float h = acc[i][j][q] + bias;
          h = fmaxf(h, 0.f);
          sum += cmv[r + q] * h;
        }
      }
      sum += __shfl_xor(sum, 16);
      sum += __shfl_xor(sum, 32);
      if (fq == 0) atomicAdd(&g[c], sum);
    }
  }
}

// ---------------- softmax stage ----------------

__global__ __launch_bounds__(256) void rowfin(const float* __restrict__ Pr,
                                              float* __restrict__ rowmax,
                                              float* __restrict__ rowinv) {
  int row = blockIdx.x * 4 + (threadIdx.x >> 6);
  int lane = threadIdx.x & 63;
  float2 p = ((const float2*)Pr)[(size_t)row * 64 + lane];
  float vm = p.x;
#pragma unroll
  for (int d = 1; d < 64; d <<= 1) vm = fmaxf(vm, __shfl_xor(vm, d));
  float s = p.y * __expf(p.x - vm);
#pragma unroll
  for (int d = 1; d < 64; d <<= 1) s += __shfl_xor(s, d);
  if (lane == 0) {
    rowmax[row] = vm;
    rowinv[row] = 1.f / s;
  }
}

__global__ __launch_bounds__(256) void rowpass(const short* __restrict__ LT,
                                               const float* __restrict__ rowmax,
                                               const float* __restrict__ rowinv,
                                               short* __restrict__ DwT,
                                               float* __restrict__ colinv,
                                               float* __restrict__ Cm) {
  int b = blockIdx.y;
  int np0 = blockIdx.x * 64;
  int wave = threadIdx.x >> 6, lane = threadIdx.x & 63;
  const float* rmax = rowmax + (b << 10);
  const float* rinv = rowinv + (b << 10);
  int m0 = lane * 16;
  float rm[16], ri[16];
#pragma unroll
  for (int i = 0; i < 4; ++i) {
    float4 a = ((const float4*)(rmax + m0))[i];
    rm[i * 4 + 0] = a.x; rm[i * 4 + 1] = a.y; rm[i * 4 + 2] = a.z; rm[i * 4 + 3] = a.w;
    float4 c = ((const float4*)(rinv + m0))[i];
    ri[i * 4 + 0] = c.x; ri[i * 4 + 1] = c.y; ri[i * 4 + 2] = c.z; ri[i * 4 + 3] = c.w;
  }
  for (int rr = wave; rr < 64; rr += 4) {
    int np = np0 + rr;
    size_t rowoff = (size_t)(b * 4096 + np) << 10;
    const f16x8* src = (const f16x8*)(LT + rowoff + m0);
    f16x8 h0 = src[0], h1 = src[1];
    float v[16];
#pragma unroll
    for (int k = 0; k < 8; ++k) { v[k] = (float)h0[k]; v[8 + k] = (float)h1[k]; }
    float vm = v[0];
#pragma unroll
    for (int k = 1; k < 16; ++k) vm = fmaxf(vm, v[k]);
#pragma unroll
    for (int d = 1; d < 64; d <<= 1) vm = fmaxf(vm, __shfl_xor(vm, d));
    float csum = 0.f, cms = 0.f;
    union { short s[16]; int4 q4[2]; } pk;
#pragma unroll
    for (int k = 0; k < 16; ++k) {
      float e = __expf(v[k] - vm);
      csum += e;
      pk.s[k] = f2bf(e);
      cms += __expf(v[k] - rm[k]) * ri[k];
    }
#pragma unroll
    for (int d = 1; d < 64; d <<= 1) {
      csum += __shfl_xor(csum, d);
      cms += __shfl_xor(cms, d);
    }
    int4* dst = (int4*)(DwT + rowoff + m0);
    dst[0] = pk.q4[0];
    dst[1] = pk.q4[1];
    if (lane == 0) {
      colinv[(b << 12) + np] = 1.f / csum;
      Cm[(b << 12) + np] = cms * (1.f / 1024.f);
    }
  }
}

// ---------------- final combine ----------------

__global__ __launch_bounds__(512) void yinit(const float* __restrict__ Cm,
                                             const float* __restrict__ b2,
                                             float* __restrict__ Y) {
  __shared__ float s[8];
  int b = blockIdx.x;
  int w = threadIdx.x >> 6, l = threadIdx.x & 63;
  float acc = 0.f;
  for (int p = l; p < 512; p += 64) acc += Cm[(b * 8 + w) * 512 + p];
  for (int d = 32; d; d >>= 1) acc += __shfl_xor(acc, d);
  if (l == 0) s[w] = acc;
  __syncthreads();
  int o = threadIdx.x;
  float yv = 0.f;
#pragma unroll
  for (int n = 0; n < 8; ++n) yv += s[n] * b2[n * 512 + o];
  Y[b * 512 + o] = yv;
}

__global__ __launch_bounds__(256) void gw2(const float* __restrict__ G,
                                           const float* __restrict__ W2,
                                           float* __restrict__ Y) {
  int o = blockIdx.x * 256 + threadIdx.x;
  int k0 = blockIdx.y * 256;
  float acc[8] = {};
  for (int kk = 0; kk < 256; ++kk) {
    int k = k0 + kk;
    float w = W2[(size_t)k * 512 + o];
#pragma unroll
    for (int b = 0; b < 8; ++b) acc[b] += G[b * 8192 + k] * w;
  }
#pragma unroll
  for (int b = 0; b < 8; ++b) atomicAdd(&Y[b * 512 + o], acc[b]);
}

// ---------------- launch ----------------

extern "C" void kernel_launch(void* const* d_in, const int* in_sizes, int n_in,
                              void* d_out, int out_size, void* d_ws, size_t ws_size,
                              hipStream_t stream) {
  const float* x = (const float*)d_in[0];
  const float* phi = (const float*)d_in[1];
  const float* W1 = (const float*)d_in[2];
  const float* b1 = (const float*)d_in[3];
  const float* W2 = (const float*)d_in[4];
  const float* b2 = (const float*)d_in[5];
  float* Y = (float*)d_out;

  size_t off = 0;
  auto alloc = [&](size_t n) {
    void* p = (char*)d_ws + off;
    off += (n + 255) & ~(size_t)255;
    return p;
  };
  short* LT = (short*)alloc(8ull * 4096 * 1024 * 2);  // 67.1 MB; Xs aliases
  short* Xs = LT;
  short* DwT = (short*)alloc(8ull * 4096 * 1024 * 2);  // 67.1 MB
  short* xh = DwT;                                     // fp16 (dead after gemm0)
  short* pT = DwT + 8ull * 1024 * 1024;                // fp16 (dead after gemm0)
  short* xT = (short*)alloc(8ull * 1024 * 1024 * 2);   // bf16, live thru gemm1
  short* W1T = (short*)alloc(8ull * 1024 * 1024 * 2);  // bf16, live thru gemm2
  float* Pr = (float*)alloc(8ull * 1024 * 64 * 2 * 4); // 4 MB partials
  float* rowmaxv = (float*)alloc(8192 * 4);
  float* rowinvv = (float*)alloc(8192 * 4);
  float* colinvv = (float*)alloc(32768 * 4);
  float* CmB = (float*)alloc(32768 * 4);
  float* G = (float*)alloc(8ull * 8192 * 4);

  conv_x<<<dim3(256, 8), 256, 0, stream>>>(x, xh, xT);
  conv_phi<<<dim3(1024), 256, 0, stream>>>(phi, pT);
  conv_w1<<<dim3(256, 8), 256, 0, stream>>>(W1, W1T);

  // LT = (xh * pT)^T fp16 + Cw partials.  M=1024,N=4096 -> 4x16 tiles
  gemm_k<0><<<dim3(64, 8), 512, 0, stream>>>(xh, pT, Pr, LT,
                                             nullptr, nullptr, nullptr, nullptr);
  rowfin<<<dim3(2048), 256, 0, stream>>>(Pr, rowmaxv, rowinvv);
  rowpass<<<dim3(64, 8), 256, 0, stream>>>(LT, rowmaxv, rowinvv, DwT, colinvv, CmB);

  // Xs = (DwT * xT) * colinv.  M=4096,N=1024 -> 16x4 tiles
  gemm_k<1><<<dim3(64, 8), 512, 0, stream>>>(DwT, xT, nullptr, Xs,
                                             colinvv, nullptr, nullptr, nullptr);

  zeroG<<<dim3(256), 256, 0, stream>>>(G);
  // G[b,n,h] = sum_p Cm * relu(Xs*W1T + b1).  M=512,N=1024 -> 2x4 tiles
  gemm_k<2><<<dim3(8, 64), 512, 0, stream>>>(Xs, W1T, nullptr, nullptr,
                                             nullptr, CmB, b1, G);

  yinit<<<dim3(8), 512, 0, stream>>>(CmB, b2, Y);
  gw2<<<dim3(2, 32), 256, 0, stream>>>(G, W2, Y);
}